// Round 10
// baseline (247.352 us; speedup 1.0000x reference)
//
#include <hip/hip_runtime.h>
#include <cstddef>

// Voxel encoder: B=2, N=16384, G=512 voxels x K=32 pts, d=128, S=2 layers.
// Round 10: LDS diet 63.5KB -> 52.6KB => 3 blocks/CU (24 waves) so voxel
// blocks overlap each other's barrier bubbles. feats_s dropped (layer0 +
// trans A-frags convert gathered fp32 rows straight from global, L1-hot);
// P folded into qk_s padding (stride 440, cols 408..439); pooled aliased
// onto red_s. __launch_bounds__(512,6) holds VGPR <= ~80 (measured 76).

#define D_   128
#define VSF  0.25f
#define QSF  0.01f
#define LQ   50
#define G_   512
#define KP   32
#define BB   2
#define NP   16384
#define MT   32768
#define SCALE 0.08838834764831845f   // 1/sqrt(128)
#define NT_ALL 34           // 24 qkv tiles + 10 dk tiles (cols 0..543)
#define FRAG_S (NT_ALL * 4 * 64 * 8)   // ushorts per layer frag buffer

using short8 = __attribute__((ext_vector_type(8))) short;
using f32x4  = __attribute__((ext_vector_type(4))) float;

__device__ inline unsigned short f2bf(float x) {
  unsigned u = __builtin_bit_cast(unsigned, x);
  u += 0x7fffu + ((u >> 16) & 1u);      // round-to-nearest-even
  return (unsigned short)(u >> 16);
}
__device__ inline float bu(unsigned short h) {
  return __builtin_bit_cast(float, (unsigned)h << 16);
}
__device__ inline short8 as_short8(uint4 v) {
  union { uint4 u; short8 s; } x; x.u = v; return x.s;
}
__device__ inline uint4 cvt8(const float* __restrict__ src) {
  float4 a0 = *(const float4*)(src);
  float4 a1 = *(const float4*)(src + 4);
  uint4 o;
  o.x = f2bf(a0.x) | ((unsigned)f2bf(a0.y) << 16);
  o.y = f2bf(a0.z) | ((unsigned)f2bf(a0.w) << 16);
  o.z = f2bf(a1.x) | ((unsigned)f2bf(a1.y) << 16);
  o.w = f2bf(a1.z) | ((unsigned)f2bf(a1.w) << 16);
  return o;
}

// ---------------------------------------------------------------------------
// Transpose the (s,1) table slices into Tt[s][e=128][c=256], c = axis*50+l,
// zero-padded for c in [150,256). grid = 256 (s*128+e), block = 256 (c).
// ---------------------------------------------------------------------------
__global__ __launch_bounds__(256) void prep_tt(
    const float* __restrict__ tbl_x, const float* __restrict__ tbl_y,
    const float* __restrict__ tbl_z, float* __restrict__ Tt)
{
  const int c = threadIdx.x;
  const int s = blockIdx.x >> 7;
  const int e = blockIdx.x & 127;
  float v = 0.f;
  if (c < 150) {
    const int axis = c / 50, l = c - axis * 50;
    const float* tb = (axis == 0 ? tbl_x : (axis == 1 ? tbl_y : tbl_z));
    v = tb[(((size_t)s * 3 + 1) * LQ + l) * D_ + e];
  }
  Tt[((size_t)(s * 128 + e)) * 256 + c] = v;
}

// ---------------------------------------------------------------------------
// Wf = Wk @ Tt (fp32, both layers). grid=(2,2,2): x=m-tile, y=n-tile, z=s.
// ---------------------------------------------------------------------------
__global__ __launch_bounds__(256) void wf_gemm(
    const float* __restrict__ qkv_w, const float* __restrict__ Tt,
    float* __restrict__ Wf)
{
  __shared__ __align__(16) float A_s[16][68];
  __shared__ __align__(16) float B_s[16][132];
  const int t  = threadIdx.x;
  const int s  = blockIdx.z;
  const float* A = qkv_w + (size_t)s * 128 * 384 + 128;   // Wk rows, lda=384
  const float* B = Tt + (size_t)s * 128 * 256;
  float* C       = Wf + (size_t)s * 128 * 256;
  const int m0 = blockIdx.x * 64;
  const int n0 = blockIdx.y * 128;
  const int r  = t >> 2;
  const int kq = (t & 3) * 4;
  const float* arow = A + (size_t)(m0 + r) * 384;
  const int kkb = t >> 4;
  const int cb  = (t & 15) * 8;
  const float* wbase = B + (size_t)kkb * 256 + n0 + cb;
  const int tx = t & 31, ty = t >> 5;

  float acc[8][4];
  #pragma unroll
  for (int i = 0; i < 8; i++)
    #pragma unroll
    for (int j = 0; j < 4; j++) acc[i][j] = 0.f;

  for (int k0 = 0; k0 < 128; k0 += 16) {
    float4 av = *(const float4*)(arow + k0 + kq);
    float4 b0 = *(const float4*)(wbase + (size_t)k0 * 256);
    float4 b1 = *(const float4*)(wbase + (size_t)k0 * 256 + 4);
    __syncthreads();
    A_s[kq + 0][r] = av.x;
    A_s[kq + 1][r] = av.y;
    A_s[kq + 2][r] = av.z;
    A_s[kq + 3][r] = av.w;
    *(float4*)&B_s[kkb][cb]     = b0;
    *(float4*)&B_s[kkb][cb + 4] = b1;
    __syncthreads();
    #pragma unroll
    for (int kk = 0; kk < 16; kk++) {
      float4 a03 = *(const float4*)&A_s[kk][ty * 8];
      float4 a47 = *(const float4*)&A_s[kk][ty * 8 + 4];
      float4 bv  = *(const float4*)&B_s[kk][tx * 4];
      float a[8] = {a03.x, a03.y, a03.z, a03.w, a47.x, a47.y, a47.z, a47.w};
      float bj[4] = {bv.x, bv.y, bv.z, bv.w};
      #pragma unroll
      for (int i = 0; i < 8; i++)
        #pragma unroll
        for (int j = 0; j < 4; j++)
          acc[i][j] += a[i] * bj[j];
    }
  }
  #pragma unroll
  for (int i = 0; i < 8; i++) {
    float4 o = {acc[i][0], acc[i][1], acc[i][2], acc[i][3]};
    *(float4*)(C + (size_t)(m0 + ty * 8 + i) * 256 + n0 + tx * 4) = o;
  }
}

// ---------------------------------------------------------------------------
// pack2: all fragment packing + combined bias in one launch. 370 blocks x 64.
// ---------------------------------------------------------------------------
__global__ __launch_bounds__(64) void pack2(
    const float* __restrict__ qkv_w, const float* __restrict__ Wf,
    const float* __restrict__ trans_w, const float* __restrict__ qkv_b,
    const float* __restrict__ Tt,
    unsigned short* __restrict__ allfrag,
    unsigned short* __restrict__ transfrag,
    float* __restrict__ bc)
{
  const int blk = blockIdx.x;
  const int lane = threadIdx.x;
  const float* B; int ldb, dstidx; unsigned short* dst; int kbase, n;
  if (blk < 192) {
    const int s = blk / 96, r = blk - s * 96;
    const int nt = r >> 2, ks = r & 3;
    B = qkv_w + (size_t)s * 128 * 384; ldb = 384;
    n = nt * 16 + (lane & 15);
    kbase = ks * 32 + ((lane >> 4) * 8);
    dst = allfrag + (size_t)s * FRAG_S;
    dstidx = nt * 4 + ks;
  } else if (blk < 272) {
    const int s = (blk - 192) / 40, r = (blk - 192) - s * 40;
    const int snt = r >> 2, ks = r & 3;
    B = Wf + (size_t)s * 32768; ldb = 256;
    n = snt * 16 + (lane & 15);
    kbase = ks * 32 + ((lane >> 4) * 8);
    dst = allfrag + (size_t)s * FRAG_S;
    dstidx = (24 + snt) * 4 + ks;
  } else if (blk < 368) {
    const int r = blk - 272;
    const int nt = r / 12, ks = r - nt * 12;
    B = trans_w; ldb = 128;
    n = nt * 16 + (lane & 15);
    kbase = ks * 32 + ((lane >> 4) * 8);
    dst = transfrag;
    dstidx = nt * 12 + ks;
  } else {
    const int s = blk - 368;
    for (int c = lane; c < 544; c += 64) {
      float v;
      if (c < 384) {
        v = qkv_b[s * 384 + c];
      } else {
        const float* bk = qkv_b + (size_t)s * 384 + 128;
        const float* T  = Tt + (size_t)s * 128 * 256 + (c - 384);
        float a = 0.f;
        #pragma unroll 4
        for (int e = 0; e < 128; e++) a += bk[e] * T[(size_t)e * 256];
        v = a;
      }
      bc[s * 544 + c] = v;
    }
    return;
  }
  unsigned v[4];
  #pragma unroll
  for (int h = 0; h < 4; h++) {
    const float x0 = B[(size_t)(kbase + 2 * h) * ldb + n];
    const float x1 = B[(size_t)(kbase + 2 * h + 1) * ldb + n];
    v[h] = f2bf(x0) | ((unsigned)f2bf(x1) << 16);
  }
  uint4 o = {v[0], v[1], v[2], v[3]};
  *(uint4*)(dst + ((size_t)dstidx * 64 + lane) * 8) = o;
}

// ---------------------------------------------------------------------------
// MEGA: one block (8 waves, 512 threads) per voxel; whole network per voxel.
// LDS 52.6KB -> 3 blocks/CU -> 24 waves/CU. grid = 1024.
// qk_s row layout (stride 440): q 0:128 (later f2) | k 128:256 | dk 256:406
//                              | P (bf16 attn) 408:440.
// V lives transposed in vT_s[f][j]. feats come straight from global (fp32).
// ---------------------------------------------------------------------------
__global__ __launch_bounds__(512, 6) void mega(
    const float* __restrict__ inputs,
    const float* __restrict__ coords,
    const int*   __restrict__ groups,
    const unsigned short* __restrict__ allfrag,   // 2 x FRAG_S
    const float* __restrict__ bc,                 // 2 x 544
    const unsigned short* __restrict__ transfrag, // 8 nt x 12 ks
    const float* __restrict__ trans_b, const float* __restrict__ ln_g,
    const float* __restrict__ ln_b,
    float* __restrict__ out_all)
{
  __shared__ __align__(16) unsigned short f1_s[32][136];
  __shared__ __align__(16) unsigned short qk_s[32][440];   // q|k|dk|P; f2->q
  __shared__ __align__(16) unsigned short vT_s[128][40];   // V^T [f][j]
  __shared__ __align__(16) float sc_s[32 * 33];
  __shared__ float cs[32][4];
  __shared__ float red_s[8][16][2];
  __shared__ float wmax_s[2][128];
  float* pooled_s = &red_s[0][0][0];   // alias: red dead before pooled written

  const int t   = threadIdx.x;
  const int bid = blockIdx.x;
  const int b   = bid >> 9;
  const int g   = bid & 511;
  const int wv = t >> 6, lane = t & 63, quad = lane >> 4, col = lane & 15;

  if (t < 32) {
    const int pid = groups[(b << 14) + g * KP + t];
    const float* cp = coords + ((size_t)(b << 14) + (size_t)pid) * 3;
    cs[t][0] = cp[0]; cs[t][1] = cp[1]; cs[t][2] = cp[2];
  }

  // gathered fp32 input row for this lane's A-row (phase A layer0 + trans)
  const int rt   = wv & 1;                  // row half
  const int rowm = rt * 16 + col;
  const int pidA = groups[(b << 14) + g * KP + rowm];
  const float* inrow = inputs + ((size_t)(b << 14) + (size_t)pidA) * D_;

  // ---- per-wave tile assignment for phase A (8 waves) ----
  const int starts[4] = {0, 9, 18, 26};
  const int range = wv >> 1;            // 4 tile ranges (9,9,8,8 tiles)
  const int start = starts[range];
  const int cnt   = (range < 2) ? 9 : 8;

  __syncthreads();   // cs ready

  for (int layer = 0; layer < 2; layer++) {
    const uint4* fr = (const uint4*)(allfrag + (size_t)layer * FRAG_S) + lane;
    const float* bcl = bc + layer * 544;

    // Phase A: qkv+dk GEMM, tile-pairs, preloaded A-frags (low VGPR).
    uint4 avu[4];
    if (layer == 0) {
      #pragma unroll
      for (int ks = 0; ks < 4; ks++)
        avu[ks] = cvt8(inrow + ks * 32 + quad * 8);
    } else {
      #pragma unroll
      for (int ks = 0; ks < 4; ks++)
        avu[ks] = *(const uint4*)&f1_s[rowm][ks * 32 + quad * 8];
    }

    #pragma unroll
    for (int u0 = 0; u0 < 10; u0 += 2) {
      f32x4 pacc[2];
      pacc[0] = (f32x4){0.f, 0.f, 0.f, 0.f};
      pacc[1] = (f32x4){0.f, 0.f, 0.f, 0.f};
      #pragma unroll
      for (int ks = 0; ks < 4; ks++) {
        short8 av = as_short8(avu[ks]);
        #pragma unroll
        for (int h = 0; h < 2; h++) {
          if (u0 + h < cnt) {
            short8 bv = as_short8(fr[((start + u0 + h) * 4 + ks) * 64]);
            pacc[h] = __builtin_amdgcn_mfma_f32_16x16x32_bf16(av, bv, pacc[h], 0, 0, 0);
          }
        }
      }
      #pragma unroll
      for (int h = 0; h < 2; h++) {
        if (u0 + h < cnt) {
          const int cc = (start + u0 + h) * 16 + col;
          const float bsv = bcl[cc];
          if (cc >= 256 && cc < 384) {          // V tile -> vT_s[f][j], b64
            const unsigned lo = f2bf(pacc[h][0] + bsv)
                              | ((unsigned)f2bf(pacc[h][1] + bsv) << 16);
            const unsigned hi = f2bf(pacc[h][2] + bsv)
                              | ((unsigned)f2bf(pacc[h][3] + bsv) << 16);
            uint2 w = {lo, hi};
            *(uint2*)&vT_s[cc - 256][rt * 16 + quad * 4] = w;
          } else {
            const int ccol = (cc < 256) ? cc : cc - 128;   // dk -> 256..405
            #pragma unroll
            for (int reg = 0; reg < 4; reg++)
              qk_s[rt * 16 + quad * 4 + reg][ccol] = f2bf(pacc[h][reg] + bsv);
          }
        }
      }
    }
    __syncthreads();

    // scores via MFMA from LDS frags (waves 0..3)
    if (wv < 4) {
      const int ihalf = wv >> 1, jhalf = wv & 1;
      f32x4 sacc = {0.f, 0.f, 0.f, 0.f};
      #pragma unroll
      for (int ks = 0; ks < 4; ks++) {
        short8 qv = as_short8(*(const uint4*)&qk_s[ihalf * 16 + col][ks * 32 + quad * 8]);
        short8 kv = as_short8(*(const uint4*)&qk_s[jhalf * 16 + col][128 + ks * 32 + quad * 8]);
        sacc = __builtin_amdgcn_mfma_f32_16x16x32_bf16(qv, kv, sacc, 0, 0, 0);
      }
      const int j = jhalf * 16 + col;
      const float cjx = cs[j][0], cjy = cs[j][1], cjz = cs[j][2];
      #pragma unroll
      for (int reg = 0; reg < 4; reg++) {
        const int i = ihalf * 16 + quad * 4 + reg;
        const float dx = cs[i][0] - cjx;
        const float dy = cs[i][1] - cjy;
        const float dz = cs[i][2] - cjz;
        int ix = (int)floorf((dx + VSF) / QSF);
        int iy = (int)floorf((dy + VSF) / QSF);
        int iz = (int)floorf((dz + VSF) / QSF);
        ix = ix < 0 ? 0 : (ix > 49 ? 49 : ix);
        iy = iy < 0 ? 0 : (iy > 49 ? 49 : iy);
        iz = iz < 0 ? 0 : (iz > 49 ? 49 : iz);
        const unsigned short* dki = &qk_s[i][256];
        const float biasv = bu(dki[ix]) + bu(dki[50 + iy]) + bu(dki[100 + iz]);
        sc_s[i * 33 + j] = (sacc[reg] + biasv) * SCALE;
      }
    }
    __syncthreads();

    // softmax: 8 threads per row (t<256); emit bf16 P into qk_s cols 408..439
    if (t < 256) {
      const int p = t >> 3, sg = t & 7;
      float vals[4];
      float lm = -1e30f;
      #pragma unroll
      for (int u = 0; u < 4; u++) {
        vals[u] = sc_s[p * 33 + sg + u * 8];
        lm = fmaxf(lm, vals[u]);
      }
      lm = fmaxf(lm, __shfl_xor(lm, 1));
      lm = fmaxf(lm, __shfl_xor(lm, 2));
      lm = fmaxf(lm, __shfl_xor(lm, 4));
      float ls = 0.f;
      #pragma unroll
      for (int u = 0; u < 4; u++) { vals[u] = __expf(vals[u] - lm); ls += vals[u]; }
      ls += __shfl_xor(ls, 1);
      ls += __shfl_xor(ls, 2);
      ls += __shfl_xor(ls, 4);
      const float inv = 1.f / ls;
      #pragma unroll
      for (int u = 0; u < 4; u++)
        qk_s[p][408 + sg + u * 8] = f2bf(vals[u] * inv);
    }
    __syncthreads();

    // PV via MFMA: wave wv does mt=wv&1, ftiles (wv>>1)*2 + {0,1}
    {
      const int mt = wv & 1, ftb = (wv >> 1) * 2;
      unsigned short* dst_base = (layer == 0) ? &f1_s[0][0] : &qk_s[0][0];
      const int dst_ld = (layer == 0) ? 136 : 440;
      short8 pv = as_short8(*(const uint4*)&qk_s[mt * 16 + col][408 + quad * 8]);
      #pragma unroll
      for (int u = 0; u < 2; u++) {
        const int ft = ftb + u;
        short8 vv = as_short8(*(const uint4*)&vT_s[ft * 16 + col][quad * 8]);
        f32x4 o = (f32x4){0.f, 0.f, 0.f, 0.f};
        o = __builtin_amdgcn_mfma_f32_16x16x32_bf16(pv, vv, o, 0, 0, 0);
        const int f = ft * 16 + col;
        #pragma unroll
        for (int reg = 0; reg < 4; reg++) {
          const int i = mt * 16 + quad * 4 + reg;
          dst_base[i * dst_ld + f] = f2bf(o[reg]);
        }
      }
    }
    __syncthreads();
  }

  // ---- trans GEMM (K=384: feats|f1|f2) + LN + ReLU + maxpool + outputs ----
  const int mtile = rt, colq = wv >> 1;   // 2 ntiles per wave
  f32x4 tacc[2];
  tacc[0] = (f32x4){0.f, 0.f, 0.f, 0.f};
  tacc[1] = (f32x4){0.f, 0.f, 0.f, 0.f};
  const uint4* tf = (const uint4*)transfrag + lane;
  #pragma unroll
  for (int ks = 0; ks < 12; ks++) {
    short8 av;
    if (ks < 4) {
      av = as_short8(cvt8(inrow + ks * 32 + quad * 8));           // feats
    } else if (ks < 8) {
      av = as_short8(*(const uint4*)&f1_s[mtile * 16 + col][(ks & 3) * 32 + quad * 8]);
    } else {
      av = as_short8(*(const uint4*)&qk_s[mtile * 16 + col][(ks & 3) * 32 + quad * 8]); // f2
    }
    #pragma unroll
    for (int u = 0; u < 2; u++) {
      const int nt = colq * 2 + u;
      short8 bv = as_short8(tf[(nt * 12 + ks) * 64]);
      tacc[u] = __builtin_amdgcn_mfma_f32_16x16x32_bf16(av, bv, tacc[u], 0, 0, 0);
    }
  }
  // bias + LN partial stats (32 cols per wave)
  float s[4] = {0.f, 0.f, 0.f, 0.f}, ssq[4] = {0.f, 0.f, 0.f, 0.f};
  float gg[2], lb[2];
  #pragma unroll
  for (int u = 0; u < 2; u++) {
    const int c = (colq * 2 + u) * 16 + col;
    const float bsv = trans_b[c];
    gg[u] = ln_g[c]; lb[u] = ln_b[c];
    #pragma unroll
    for (int reg = 0; reg < 4; reg++) {
      const float v = tacc[u][reg] + bsv;
      tacc[u][reg] = v;
      s[reg] += v; ssq[reg] += v * v;
    }
  }
  #pragma unroll
  for (int mk = 1; mk <= 8; mk <<= 1) {
    #pragma unroll
    for (int reg = 0; reg < 4; reg++) {
      s[reg]   += __shfl_xor(s[reg],   mk);
      ssq[reg] += __shfl_xor(ssq[reg], mk);
    }
  }
  if (col == 0) {
    #pragma unroll
    for (int reg = 0; reg < 4; reg++) {
      red_s[wv][quad * 4 + reg][0] = s[reg];
      red_s[wv][quad * 4 + reg][1] = ssq[reg];
    }
  }
  __syncthreads();
  float mu[4], rstd[4];
  #pragma unroll
  for (int reg = 0; reg < 4; reg++) {
    float st = 0.f, sst = 0.f;
    #pragma unroll
    for (int w = 0; w < 4; w++) {
      st  += red_s[mtile + w * 2][quad * 4 + reg][0];
      sst += red_s[mtile + w * 2][quad * 4 + reg][1];
    }
    mu[reg] = st * (1.f / 128.f);
    const float var = sst * (1.f / 128.f) - mu[reg] * mu[reg];
    rstd[reg] = rsqrtf(var + 1e-5f);
  }
  // LN + ReLU + column max over this wave's 16 rows
  float cm[2];
  #pragma unroll
  for (int u = 0; u < 2; u++) {
    float mx = 0.f;   // ReLU floor
    #pragma unroll
    for (int reg = 0; reg < 4; reg++) {
      float v = (tacc[u][reg] - mu[reg]) * rstd[reg] * gg[u] + lb[u];
      v = fmaxf(v, 0.f);
      mx = fmaxf(mx, v);
    }
    cm[u] = mx;
  }
  #pragma unroll
  for (int u = 0; u < 2; u++) {
    cm[u] = fmaxf(cm[u], __shfl_xor(cm[u], 16));
    cm[u] = fmaxf(cm[u], __shfl_xor(cm[u], 32));
  }
  __syncthreads();   // red_s reads done everywhere (pooled aliases red_s)
  if (quad == 0) {
    #pragma unroll
    for (int u = 0; u < 2; u++)
      wmax_s[mtile][(colq * 2 + u) * 16 + col] = cm[u];
  }
  __syncthreads();

  // pooled = max over both row halves; grid-reordered out write
  if (t < 128) {
    const int c = t;
    const float mx = fmaxf(wmax_s[0][c], wmax_s[1][c]);
    pooled_s[c] = mx;
    const int mm = g >> 6, nn = (g >> 3) & 7, tt2 = g & 7;
    const int opos = tt2 * 64 + nn * 8 + mm;
    out_all[((size_t)b * G_ + opos) * D_ + c] = mx;
  }
  __syncthreads();

  // scatter pooled to every point (for_ret); 256 threads, 16 floats each
  if (t < 256) {
    const int p = t >> 3, sg = t & 7;
    const int pid = groups[(b << 14) + g * KP + p];
    float* dst = out_all + (size_t)BB * G_ * D_
               + ((size_t)(b << 14) + (size_t)pid) * D_ + sg * 16;
    #pragma unroll
    for (int u = 0; u < 4; u++)
      *(float4*)(dst + u * 4) = *(const float4*)&pooled_s[sg * 16 + u * 4];
  }
}

// ---------------------------------------------------------------------------
extern "C" void kernel_launch(void* const* d_in, const int* in_sizes, int n_in,
                              void* d_out, int out_size, void* d_ws, size_t ws_size,
                              hipStream_t stream) {
  const float* inputs  = (const float*)d_in[0];
  const float* coords  = (const float*)d_in[1];
  const float* qkv_w   = (const float*)d_in[2];   // [2,128,384]
  const float* qkv_b   = (const float*)d_in[3];   // [2,384]
  const float* tbl_x   = (const float*)d_in[4];   // [2,3,50,128]
  const float* tbl_y   = (const float*)d_in[5];
  const float* tbl_z   = (const float*)d_in[6];
  const float* trans_w = (const float*)d_in[7];   // [384,128]
  const float* trans_b = (const float*)d_in[8];
  const float* ln_g    = (const float*)d_in[9];
  const float* ln_b    = (const float*)d_in[10];
  const int*   groups  = (const int*)d_in[11];    // [2,512,32] flat

  float* out = (float*)d_out;
  unsigned short* allfrag   = (unsigned short*)d_ws;       // 2*FRAG_S
  unsigned short* transfrag = allfrag + 2 * FRAG_S;        // 96*512
  float* Tt  = (float*)(transfrag + 96 * 512);             // 2*128*256 f32
  float* Wf  = Tt + (size_t)2 * 128 * 256;                 // 2*128*256 f32
  float* bc  = Wf + (size_t)2 * 128 * 256;                 // 2*544 f32

  // ---- prep (weights only) ----
  prep_tt<<<256, 256, 0, stream>>>(tbl_x, tbl_y, tbl_z, Tt);
  wf_gemm<<<dim3(2, 2, 2), 256, 0, stream>>>(qkv_w, Tt, Wf);
  pack2<<<370, 64, 0, stream>>>(qkv_w, Wf, trans_w, qkv_b, Tt,
                                allfrag, transfrag, bc);

  // ---- whole network, one kernel ----
  mega<<<BB * G_, 512, 0, stream>>>(inputs, coords, groups, allfrag, bc,
                                    transfrag, trans_b, ln_g, ln_b, out);
}

// Round 11
// 203.448 us; speedup vs baseline: 1.2158x; 1.2158x over previous
//
#include <hip/hip_runtime.h>
#include <cstddef>

// Voxel encoder: B=2, N=16384, G=512 voxels x K=32 pts, d=128, S=2 layers.
// Round 11: round-10 LDS diet (52.6KB -> 3 blocks/CU possible) but with
// __launch_bounds__(512,2). RULE (measured r8: (512,4)->64 VGPR, r10:
// (512,6)->40 VGPR): forcing min-waves on this kernel caps VGPRs below
// phase A's ~76 live regs and spills ~240MB/dispatch through scratch.
// With cap 256 the compiler lands ~76-84 VGPRs (r9), which still permits
// 6 waves/SIMD => 3 LDS-limited blocks/CU without any forced cap.

#define D_   128
#define VSF  0.25f
#define QSF  0.01f
#define LQ   50
#define G_   512
#define KP   32
#define BB   2
#define NP   16384
#define MT   32768
#define SCALE 0.08838834764831845f   // 1/sqrt(128)
#define NT_ALL 34           // 24 qkv tiles + 10 dk tiles (cols 0..543)
#define FRAG_S (NT_ALL * 4 * 64 * 8)   // ushorts per layer frag buffer

using short8 = __attribute__((ext_vector_type(8))) short;
using f32x4  = __attribute__((ext_vector_type(4))) float;

__device__ inline unsigned short f2bf(float x) {
  unsigned u = __builtin_bit_cast(unsigned, x);
  u += 0x7fffu + ((u >> 16) & 1u);      // round-to-nearest-even
  return (unsigned short)(u >> 16);
}
__device__ inline float bu(unsigned short h) {
  return __builtin_bit_cast(float, (unsigned)h << 16);
}
__device__ inline short8 as_short8(uint4 v) {
  union { uint4 u; short8 s; } x; x.u = v; return x.s;
}
__device__ inline uint4 cvt8(const float* __restrict__ src) {
  float4 a0 = *(const float4*)(src);
  float4 a1 = *(const float4*)(src + 4);
  uint4 o;
  o.x = f2bf(a0.x) | ((unsigned)f2bf(a0.y) << 16);
  o.y = f2bf(a0.z) | ((unsigned)f2bf(a0.w) << 16);
  o.z = f2bf(a1.x) | ((unsigned)f2bf(a1.y) << 16);
  o.w = f2bf(a1.z) | ((unsigned)f2bf(a1.w) << 16);
  return o;
}

// ---------------------------------------------------------------------------
// Transpose the (s,1) table slices into Tt[s][e=128][c=256], c = axis*50+l,
// zero-padded for c in [150,256). grid = 256 (s*128+e), block = 256 (c).
// ---------------------------------------------------------------------------
__global__ __launch_bounds__(256) void prep_tt(
    const float* __restrict__ tbl_x, const float* __restrict__ tbl_y,
    const float* __restrict__ tbl_z, float* __restrict__ Tt)
{
  const int c = threadIdx.x;
  const int s = blockIdx.x >> 7;
  const int e = blockIdx.x & 127;
  float v = 0.f;
  if (c < 150) {
    const int axis = c / 50, l = c - axis * 50;
    const float* tb = (axis == 0 ? tbl_x : (axis == 1 ? tbl_y : tbl_z));
    v = tb[(((size_t)s * 3 + 1) * LQ + l) * D_ + e];
  }
  Tt[((size_t)(s * 128 + e)) * 256 + c] = v;
}

// ---------------------------------------------------------------------------
// Wf = Wk @ Tt (fp32, both layers). grid=(2,2,2): x=m-tile, y=n-tile, z=s.
// ---------------------------------------------------------------------------
__global__ __launch_bounds__(256) void wf_gemm(
    const float* __restrict__ qkv_w, const float* __restrict__ Tt,
    float* __restrict__ Wf)
{
  __shared__ __align__(16) float A_s[16][68];
  __shared__ __align__(16) float B_s[16][132];
  const int t  = threadIdx.x;
  const int s  = blockIdx.z;
  const float* A = qkv_w + (size_t)s * 128 * 384 + 128;   // Wk rows, lda=384
  const float* B = Tt + (size_t)s * 128 * 256;
  float* C       = Wf + (size_t)s * 128 * 256;
  const int m0 = blockIdx.x * 64;
  const int n0 = blockIdx.y * 128;
  const int r  = t >> 2;
  const int kq = (t & 3) * 4;
  const float* arow = A + (size_t)(m0 + r) * 384;
  const int kkb = t >> 4;
  const int cb  = (t & 15) * 8;
  const float* wbase = B + (size_t)kkb * 256 + n0 + cb;
  const int tx = t & 31, ty = t >> 5;

  float acc[8][4];
  #pragma unroll
  for (int i = 0; i < 8; i++)
    #pragma unroll
    for (int j = 0; j < 4; j++) acc[i][j] = 0.f;

  for (int k0 = 0; k0 < 128; k0 += 16) {
    float4 av = *(const float4*)(arow + k0 + kq);
    float4 b0 = *(const float4*)(wbase + (size_t)k0 * 256);
    float4 b1 = *(const float4*)(wbase + (size_t)k0 * 256 + 4);
    __syncthreads();
    A_s[kq + 0][r] = av.x;
    A_s[kq + 1][r] = av.y;
    A_s[kq + 2][r] = av.z;
    A_s[kq + 3][r] = av.w;
    *(float4*)&B_s[kkb][cb]     = b0;
    *(float4*)&B_s[kkb][cb + 4] = b1;
    __syncthreads();
    #pragma unroll
    for (int kk = 0; kk < 16; kk++) {
      float4 a03 = *(const float4*)&A_s[kk][ty * 8];
      float4 a47 = *(const float4*)&A_s[kk][ty * 8 + 4];
      float4 bv  = *(const float4*)&B_s[kk][tx * 4];
      float a[8] = {a03.x, a03.y, a03.z, a03.w, a47.x, a47.y, a47.z, a47.w};
      float bj[4] = {bv.x, bv.y, bv.z, bv.w};
      #pragma unroll
      for (int i = 0; i < 8; i++)
        #pragma unroll
        for (int j = 0; j < 4; j++)
          acc[i][j] += a[i] * bj[j];
    }
  }
  #pragma unroll
  for (int i = 0; i < 8; i++) {
    float4 o = {acc[i][0], acc[i][1], acc[i][2], acc[i][3]};
    *(float4*)(C + (size_t)(m0 + ty * 8 + i) * 256 + n0 + tx * 4) = o;
  }
}

// ---------------------------------------------------------------------------
// pack2: all fragment packing + combined bias in one launch. 370 blocks x 64.
// ---------------------------------------------------------------------------
__global__ __launch_bounds__(64) void pack2(
    const float* __restrict__ qkv_w, const float* __restrict__ Wf,
    const float* __restrict__ trans_w, const float* __restrict__ qkv_b,
    const float* __restrict__ Tt,
    unsigned short* __restrict__ allfrag,
    unsigned short* __restrict__ transfrag,
    float* __restrict__ bc)
{
  const int blk = blockIdx.x;
  const int lane = threadIdx.x;
  const float* B; int ldb, dstidx; unsigned short* dst; int kbase, n;
  if (blk < 192) {
    const int s = blk / 96, r = blk - s * 96;
    const int nt = r >> 2, ks = r & 3;
    B = qkv_w + (size_t)s * 128 * 384; ldb = 384;
    n = nt * 16 + (lane & 15);
    kbase = ks * 32 + ((lane >> 4) * 8);
    dst = allfrag + (size_t)s * FRAG_S;
    dstidx = nt * 4 + ks;
  } else if (blk < 272) {
    const int s = (blk - 192) / 40, r = (blk - 192) - s * 40;
    const int snt = r >> 2, ks = r & 3;
    B = Wf + (size_t)s * 32768; ldb = 256;
    n = snt * 16 + (lane & 15);
    kbase = ks * 32 + ((lane >> 4) * 8);
    dst = allfrag + (size_t)s * FRAG_S;
    dstidx = (24 + snt) * 4 + ks;
  } else if (blk < 368) {
    const int r = blk - 272;
    const int nt = r / 12, ks = r - nt * 12;
    B = trans_w; ldb = 128;
    n = nt * 16 + (lane & 15);
    kbase = ks * 32 + ((lane >> 4) * 8);
    dst = transfrag;
    dstidx = nt * 12 + ks;
  } else {
    const int s = blk - 368;
    for (int c = lane; c < 544; c += 64) {
      float v;
      if (c < 384) {
        v = qkv_b[s * 384 + c];
      } else {
        const float* bk = qkv_b + (size_t)s * 384 + 128;
        const float* T  = Tt + (size_t)s * 128 * 256 + (c - 384);
        float a = 0.f;
        #pragma unroll 4
        for (int e = 0; e < 128; e++) a += bk[e] * T[(size_t)e * 256];
        v = a;
      }
      bc[s * 544 + c] = v;
    }
    return;
  }
  unsigned v[4];
  #pragma unroll
  for (int h = 0; h < 4; h++) {
    const float x0 = B[(size_t)(kbase + 2 * h) * ldb + n];
    const float x1 = B[(size_t)(kbase + 2 * h + 1) * ldb + n];
    v[h] = f2bf(x0) | ((unsigned)f2bf(x1) << 16);
  }
  uint4 o = {v[0], v[1], v[2], v[3]};
  *(uint4*)(dst + ((size_t)dstidx * 64 + lane) * 8) = o;
}

// ---------------------------------------------------------------------------
// MEGA: one block (8 waves, 512 threads) per voxel; whole network per voxel.
// LDS 52.6KB; natural VGPR ~76-84 => up to 3 blocks/CU (LDS-limited).
// qk_s row layout (stride 440): q 0:128 (later f2) | k 128:256 | dk 256:406
//                              | P (bf16 attn) 408:440.
// V lives transposed in vT_s[f][j]. feats come straight from global (fp32).
// ---------------------------------------------------------------------------
__global__ __launch_bounds__(512, 2) void mega(
    const float* __restrict__ inputs,
    const float* __restrict__ coords,
    const int*   __restrict__ groups,
    const unsigned short* __restrict__ allfrag,   // 2 x FRAG_S
    const float* __restrict__ bc,                 // 2 x 544
    const unsigned short* __restrict__ transfrag, // 8 nt x 12 ks
    const float* __restrict__ trans_b, const float* __restrict__ ln_g,
    const float* __restrict__ ln_b,
    float* __restrict__ out_all)
{
  __shared__ __align__(16) unsigned short f1_s[32][136];
  __shared__ __align__(16) unsigned short qk_s[32][440];   // q|k|dk|P; f2->q
  __shared__ __align__(16) unsigned short vT_s[128][40];   // V^T [f][j]
  __shared__ __align__(16) float sc_s[32 * 33];
  __shared__ float cs[32][4];
  __shared__ float red_s[8][16][2];
  __shared__ float wmax_s[2][128];
  float* pooled_s = &red_s[0][0][0];   // alias: red dead before pooled written

  const int t   = threadIdx.x;
  const int bid = blockIdx.x;
  const int b   = bid >> 9;
  const int g   = bid & 511;
  const int wv = t >> 6, lane = t & 63, quad = lane >> 4, col = lane & 15;

  if (t < 32) {
    const int pid = groups[(b << 14) + g * KP + t];
    const float* cp = coords + ((size_t)(b << 14) + (size_t)pid) * 3;
    cs[t][0] = cp[0]; cs[t][1] = cp[1]; cs[t][2] = cp[2];
  }

  // gathered fp32 input row for this lane's A-row (phase A layer0 + trans)
  const int rt   = wv & 1;                  // row half
  const int rowm = rt * 16 + col;
  const int pidA = groups[(b << 14) + g * KP + rowm];
  const float* inrow = inputs + ((size_t)(b << 14) + (size_t)pidA) * D_;

  // ---- per-wave tile assignment for phase A (8 waves) ----
  const int starts[4] = {0, 9, 18, 26};
  const int range = wv >> 1;            // 4 tile ranges (9,9,8,8 tiles)
  const int start = starts[range];
  const int cnt   = (range < 2) ? 9 : 8;

  __syncthreads();   // cs ready

  for (int layer = 0; layer < 2; layer++) {
    const uint4* fr = (const uint4*)(allfrag + (size_t)layer * FRAG_S) + lane;
    const float* bcl = bc + layer * 544;

    // Phase A: qkv+dk GEMM, tile-pairs, preloaded A-frags (low VGPR).
    uint4 avu[4];
    if (layer == 0) {
      #pragma unroll
      for (int ks = 0; ks < 4; ks++)
        avu[ks] = cvt8(inrow + ks * 32 + quad * 8);
    } else {
      #pragma unroll
      for (int ks = 0; ks < 4; ks++)
        avu[ks] = *(const uint4*)&f1_s[rowm][ks * 32 + quad * 8];
    }

    #pragma unroll
    for (int u0 = 0; u0 < 10; u0 += 2) {
      f32x4 pacc[2];
      pacc[0] = (f32x4){0.f, 0.f, 0.f, 0.f};
      pacc[1] = (f32x4){0.f, 0.f, 0.f, 0.f};
      #pragma unroll
      for (int ks = 0; ks < 4; ks++) {
        short8 av = as_short8(avu[ks]);
        #pragma unroll
        for (int h = 0; h < 2; h++) {
          if (u0 + h < cnt) {
            short8 bv = as_short8(fr[((start + u0 + h) * 4 + ks) * 64]);
            pacc[h] = __builtin_amdgcn_mfma_f32_16x16x32_bf16(av, bv, pacc[h], 0, 0, 0);
          }
        }
      }
      #pragma unroll
      for (int h = 0; h < 2; h++) {
        if (u0 + h < cnt) {
          const int cc = (start + u0 + h) * 16 + col;
          const float bsv = bcl[cc];
          if (cc >= 256 && cc < 384) {          // V tile -> vT_s[f][j], b64
            const unsigned lo = f2bf(pacc[h][0] + bsv)
                              | ((unsigned)f2bf(pacc[h][1] + bsv) << 16);
            const unsigned hi = f2bf(pacc[h][2] + bsv)
                              | ((unsigned)f2bf(pacc[h][3] + bsv) << 16);
            uint2 w = {lo, hi};
            *(uint2*)&vT_s[cc - 256][rt * 16 + quad * 4] = w;
          } else {
            const int ccol = (cc < 256) ? cc : cc - 128;   // dk -> 256..405
            #pragma unroll
            for (int reg = 0; reg < 4; reg++)
              qk_s[rt * 16 + quad * 4 + reg][ccol] = f2bf(pacc[h][reg] + bsv);
          }
        }
      }
    }
    __syncthreads();

    // scores via MFMA from LDS frags (waves 0..3)
    if (wv < 4) {
      const int ihalf = wv >> 1, jhalf = wv & 1;
      f32x4 sacc = {0.f, 0.f, 0.f, 0.f};
      #pragma unroll
      for (int ks = 0; ks < 4; ks++) {
        short8 qv = as_short8(*(const uint4*)&qk_s[ihalf * 16 + col][ks * 32 + quad * 8]);
        short8 kv = as_short8(*(const uint4*)&qk_s[jhalf * 16 + col][128 + ks * 32 + quad * 8]);
        sacc = __builtin_amdgcn_mfma_f32_16x16x32_bf16(qv, kv, sacc, 0, 0, 0);
      }
      const int j = jhalf * 16 + col;
      const float cjx = cs[j][0], cjy = cs[j][1], cjz = cs[j][2];
      #pragma unroll
      for (int reg = 0; reg < 4; reg++) {
        const int i = ihalf * 16 + quad * 4 + reg;
        const float dx = cs[i][0] - cjx;
        const float dy = cs[i][1] - cjy;
        const float dz = cs[i][2] - cjz;
        int ix = (int)floorf((dx + VSF) / QSF);
        int iy = (int)floorf((dy + VSF) / QSF);
        int iz = (int)floorf((dz + VSF) / QSF);
        ix = ix < 0 ? 0 : (ix > 49 ? 49 : ix);
        iy = iy < 0 ? 0 : (iy > 49 ? 49 : iy);
        iz = iz < 0 ? 0 : (iz > 49 ? 49 : iz);
        const unsigned short* dki = &qk_s[i][256];
        const float biasv = bu(dki[ix]) + bu(dki[50 + iy]) + bu(dki[100 + iz]);
        sc_s[i * 33 + j] = (sacc[reg] + biasv) * SCALE;
      }
    }
    __syncthreads();

    // softmax: 8 threads per row (t<256); emit bf16 P into qk_s cols 408..439
    if (t < 256) {
      const int p = t >> 3, sg = t & 7;
      float vals[4];
      float lm = -1e30f;
      #pragma unroll
      for (int u = 0; u < 4; u++) {
        vals[u] = sc_s[p * 33 + sg + u * 8];
        lm = fmaxf(lm, vals[u]);
      }
      lm = fmaxf(lm, __shfl_xor(lm, 1));
      lm = fmaxf(lm, __shfl_xor(lm, 2));
      lm = fmaxf(lm, __shfl_xor(lm, 4));
      float ls = 0.f;
      #pragma unroll
      for (int u = 0; u < 4; u++) { vals[u] = __expf(vals[u] - lm); ls += vals[u]; }
      ls += __shfl_xor(ls, 1);
      ls += __shfl_xor(ls, 2);
      ls += __shfl_xor(ls, 4);
      const float inv = 1.f / ls;
      #pragma unroll
      for (int u = 0; u < 4; u++)
        qk_s[p][408 + sg + u * 8] = f2bf(vals[u] * inv);
    }
    __syncthreads();

    // PV via MFMA: wave wv does mt=wv&1, ftiles (wv>>1)*2 + {0,1}
    {
      const int mt = wv & 1, ftb = (wv >> 1) * 2;
      unsigned short* dst_base = (layer == 0) ? &f1_s[0][0] : &qk_s[0][0];
      const int dst_ld = (layer == 0) ? 136 : 440;
      short8 pv = as_short8(*(const uint4*)&qk_s[mt * 16 + col][408 + quad * 8]);
      #pragma unroll
      for (int u = 0; u < 2; u++) {
        const int ft = ftb + u;
        short8 vv = as_short8(*(const uint4*)&vT_s[ft * 16 + col][quad * 8]);
        f32x4 o = (f32x4){0.f, 0.f, 0.f, 0.f};
        o = __builtin_amdgcn_mfma_f32_16x16x32_bf16(pv, vv, o, 0, 0, 0);
        const int f = ft * 16 + col;
        #pragma unroll
        for (int reg = 0; reg < 4; reg++) {
          const int i = mt * 16 + quad * 4 + reg;
          dst_base[i * dst_ld + f] = f2bf(o[reg]);
        }
      }
    }
    __syncthreads();
  }

  // ---- trans GEMM (K=384: feats|f1|f2) + LN + ReLU + maxpool + outputs ----
  const int mtile = rt, colq = wv >> 1;   // 2 ntiles per wave
  f32x4 tacc[2];
  tacc[0] = (f32x4){0.f, 0.f, 0.f, 0.f};
  tacc[1] = (f32x4){0.f, 0.f, 0.f, 0.f};
  const uint4* tf = (const uint4*)transfrag + lane;
  #pragma unroll
  for (int ks = 0; ks < 12; ks++) {
    short8 av;
    if (ks < 4) {
      av = as_short8(cvt8(inrow + ks * 32 + quad * 8));           // feats
    } else if (ks < 8) {
      av = as_short8(*(const uint4*)&f1_s[mtile * 16 + col][(ks & 3) * 32 + quad * 8]);
    } else {
      av = as_short8(*(const uint4*)&qk_s[mtile * 16 + col][(ks & 3) * 32 + quad * 8]); // f2
    }
    #pragma unroll
    for (int u = 0; u < 2; u++) {
      const int nt = colq * 2 + u;
      short8 bv = as_short8(tf[(nt * 12 + ks) * 64]);
      tacc[u] = __builtin_amdgcn_mfma_f32_16x16x32_bf16(av, bv, tacc[u], 0, 0, 0);
    }
  }
  // bias + LN partial stats (32 cols per wave)
  float s[4] = {0.f, 0.f, 0.f, 0.f}, ssq[4] = {0.f, 0.f, 0.f, 0.f};
  float gg[2], lb[2];
  #pragma unroll
  for (int u = 0; u < 2; u++) {
    const int c = (colq * 2 + u) * 16 + col;
    const float bsv = trans_b[c];
    gg[u] = ln_g[c]; lb[u] = ln_b[c];
    #pragma unroll
    for (int reg = 0; reg < 4; reg++) {
      const float v = tacc[u][reg] + bsv;
      tacc[u][reg] = v;
      s[reg] += v; ssq[reg] += v * v;
    }
  }
  #pragma unroll
  for (int mk = 1; mk <= 8; mk <<= 1) {
    #pragma unroll
    for (int reg = 0; reg < 4; reg++) {
      s[reg]   += __shfl_xor(s[reg],   mk);
      ssq[reg] += __shfl_xor(ssq[reg], mk);
    }
  }
  if (col == 0) {
    #pragma unroll
    for (int reg = 0; reg < 4; reg++) {
      red_s[wv][quad * 4 + reg][0] = s[reg];
      red_s[wv][quad * 4 + reg][1] = ssq[reg];
    }
  }
  __syncthreads();
  float mu[4], rstd[4];
  #pragma unroll
  for (int reg = 0; reg < 4; reg++) {
    float st = 0.f, sst = 0.f;
    #pragma unroll
    for (int w = 0; w < 4; w++) {
      st  += red_s[mtile + w * 2][quad * 4 + reg][0];
      sst += red_s[mtile + w * 2][quad * 4 + reg][1];
    }
    mu[reg] = st * (1.f / 128.f);
    const float var = sst * (1.f / 128.f) - mu[reg] * mu[reg];
    rstd[reg] = rsqrtf(var + 1e-5f);
  }
  // LN + ReLU + column max over this wave's 16 rows
  float cm[2];
  #pragma unroll
  for (int u = 0; u < 2; u++) {
    float mx = 0.f;   // ReLU floor
    #pragma unroll
    for (int reg = 0; reg < 4; reg++) {
      float v = (tacc[u][reg] - mu[reg]) * rstd[reg] * gg[u] + lb[u];
      v = fmaxf(v, 0.f);
      mx = fmaxf(mx, v);
    }
    cm[u] = mx;
  }
  #pragma unroll
  for (int u = 0; u < 2; u++) {
    cm[u] = fmaxf(cm[u], __shfl_xor(cm[u], 16));
    cm[u] = fmaxf(cm[u], __shfl_xor(cm[u], 32));
  }
  __syncthreads();   // red_s reads done everywhere (pooled aliases red_s)
  if (quad == 0) {
    #pragma unroll
    for (int u = 0; u < 2; u++)
      wmax_s[mtile][(colq * 2 + u) * 16 + col] = cm[u];
  }
  __syncthreads();

  // pooled = max over both row halves; grid-reordered out write
  if (t < 128) {
    const int c = t;
    const float mx = fmaxf(wmax_s[0][c], wmax_s[1][c]);
    pooled_s[c] = mx;
    const int mm = g >> 6, nn = (g >> 3) & 7, tt2 = g & 7;
    const int opos = tt2 * 64 + nn * 8 + mm;
    out_all[((size_t)b * G_ + opos) * D_ + c] = mx;
  }
  __syncthreads();

  // scatter pooled to every point (for_ret); 256 threads, 16 floats each
  if (t < 256) {
    const int p = t >> 3, sg = t & 7;
    const int pid = groups[(b << 14) + g * KP + p];
    float* dst = out_all + (size_t)BB * G_ * D_
               + ((size_t)(b << 14) + (size_t)pid) * D_ + sg * 16;
    #pragma unroll
    for (int u = 0; u < 4; u++)
      *(float4*)(dst + u * 4) = *(const float4*)&pooled_s[sg * 16 + u * 4];
  }
}

// ---------------------------------------------------------------------------
extern "C" void kernel_launch(void* const* d_in, const int* in_sizes, int n_in,
                              void* d_out, int out_size, void* d_ws, size_t ws_size,
                              hipStream_t stream) {
  const float* inputs  = (const float*)d_in[0];
  const float* coords  = (const float*)d_in[1];
  const float* qkv_w   = (const float*)d_in[2];   // [2,128,384]
  const float* qkv_b   = (const float*)d_in[3];   // [2,384]
  const float* tbl_x   = (const float*)d_in[4];   // [2,3,50,128]
  const float* tbl_y   = (const float*)d_in[5];
  const float* tbl_z   = (const float*)d_in[6];
  const float* trans_w = (const float*)d_in[7];   // [384,128]
  const float* trans_b = (const float*)d_in[8];
  const float* ln_g    = (const float*)d_in[9];
  const float* ln_b    = (const float*)d_in[10];
  const int*   groups  = (const int*)d_in[11];    // [2,512,32] flat

  float* out = (float*)d_out;
  unsigned short* allfrag   = (unsigned short*)d_ws;       // 2*FRAG_S
  unsigned short* transfrag = allfrag + 2 * FRAG_S;        // 96*512
  float* Tt  = (float*)(transfrag + 96 * 512);             // 2*128*256 f32
  float* Wf  = Tt + (size_t)2 * 128 * 256;                 // 2*128*256 f32
  float* bc  = Wf + (size_t)2 * 128 * 256;                 // 2*544 f32

  // ---- prep (weights only) ----
  prep_tt<<<256, 256, 0, stream>>>(tbl_x, tbl_y, tbl_z, Tt);
  wf_gemm<<<dim3(2, 2, 2), 256, 0, stream>>>(qkv_w, Tt, Wf);
  pack2<<<370, 64, 0, stream>>>(qkv_w, Wf, trans_w, qkv_b, Tt,
                                allfrag, transfrag, bc);

  // ---- whole network, one kernel ----
  mega<<<BB * G_, 512, 0, stream>>>(inputs, coords, groups, allfrag, bc,
                                    transfrag, trans_b, ln_g, ln_b, out);
}

// Round 12
// 168.089 us; speedup vs baseline: 1.4716x; 1.2104x over previous
//
#include <hip/hip_runtime.h>
#include <cstddef>

// Voxel encoder: B=2, N=16384, G=512 voxels x K=32 pts, d=128, S=2 layers.
// Round 12: round-9 mega (known-good 71.6us) with weight fragments read
// ONCE per block: phase A waves own 8 tile-ranges and compute BOTH row
// halves per B-frag read (r9 read each frag twice - once per row-half
// wave); trans wave=ntile computes both mtiles per frag read. Halves the
// ~750KB/block L2 weight refetch that dominates the serial chain.
// RULE (r8/r10): never force min-waves>2 - VGPR caps <=84 spill phase A.

#define D_   128
#define VSF  0.25f
#define QSF  0.01f
#define LQ   50
#define G_   512
#define KP   32
#define BB   2
#define NP   16384
#define MT   32768
#define SCALE 0.08838834764831845f   // 1/sqrt(128)
#define NT_ALL 34           // 24 qkv tiles + 10 dk tiles (cols 0..543)
#define FRAG_S (NT_ALL * 4 * 64 * 8)   // ushorts per layer frag buffer

using short8 = __attribute__((ext_vector_type(8))) short;
using f32x4  = __attribute__((ext_vector_type(4))) float;

__device__ inline unsigned short f2bf(float x) {
  unsigned u = __builtin_bit_cast(unsigned, x);
  u += 0x7fffu + ((u >> 16) & 1u);      // round-to-nearest-even
  return (unsigned short)(u >> 16);
}
__device__ inline float bu(unsigned short h) {
  return __builtin_bit_cast(float, (unsigned)h << 16);
}
__device__ inline short8 as_short8(uint4 v) {
  union { uint4 u; short8 s; } x; x.u = v; return x.s;
}

// ---------------------------------------------------------------------------
// Transpose the (s,1) table slices into Tt[s][e=128][c=256], c = axis*50+l,
// zero-padded for c in [150,256). grid = 256 (s*128+e), block = 256 (c).
// ---------------------------------------------------------------------------
__global__ __launch_bounds__(256) void prep_tt(
    const float* __restrict__ tbl_x, const float* __restrict__ tbl_y,
    const float* __restrict__ tbl_z, float* __restrict__ Tt)
{
  const int c = threadIdx.x;
  const int s = blockIdx.x >> 7;
  const int e = blockIdx.x & 127;
  float v = 0.f;
  if (c < 150) {
    const int axis = c / 50, l = c - axis * 50;
    const float* tb = (axis == 0 ? tbl_x : (axis == 1 ? tbl_y : tbl_z));
    v = tb[(((size_t)s * 3 + 1) * LQ + l) * D_ + e];
  }
  Tt[((size_t)(s * 128 + e)) * 256 + c] = v;
}

// ---------------------------------------------------------------------------
// Wf = Wk @ Tt (fp32, both layers). grid=(2,2,2): x=m-tile, y=n-tile, z=s.
// ---------------------------------------------------------------------------
__global__ __launch_bounds__(256) void wf_gemm(
    const float* __restrict__ qkv_w, const float* __restrict__ Tt,
    float* __restrict__ Wf)
{
  __shared__ __align__(16) float A_s[16][68];
  __shared__ __align__(16) float B_s[16][132];
  const int t  = threadIdx.x;
  const int s  = blockIdx.z;
  const float* A = qkv_w + (size_t)s * 128 * 384 + 128;   // Wk rows, lda=384
  const float* B = Tt + (size_t)s * 128 * 256;
  float* C       = Wf + (size_t)s * 128 * 256;
  const int m0 = blockIdx.x * 64;
  const int n0 = blockIdx.y * 128;
  const int r  = t >> 2;
  const int kq = (t & 3) * 4;
  const float* arow = A + (size_t)(m0 + r) * 384;
  const int kkb = t >> 4;
  const int cb  = (t & 15) * 8;
  const float* wbase = B + (size_t)kkb * 256 + n0 + cb;
  const int tx = t & 31, ty = t >> 5;

  float acc[8][4];
  #pragma unroll
  for (int i = 0; i < 8; i++)
    #pragma unroll
    for (int j = 0; j < 4; j++) acc[i][j] = 0.f;

  for (int k0 = 0; k0 < 128; k0 += 16) {
    float4 av = *(const float4*)(arow + k0 + kq);
    float4 b0 = *(const float4*)(wbase + (size_t)k0 * 256);
    float4 b1 = *(const float4*)(wbase + (size_t)k0 * 256 + 4);
    __syncthreads();
    A_s[kq + 0][r] = av.x;
    A_s[kq + 1][r] = av.y;
    A_s[kq + 2][r] = av.z;
    A_s[kq + 3][r] = av.w;
    *(float4*)&B_s[kkb][cb]     = b0;
    *(float4*)&B_s[kkb][cb + 4] = b1;
    __syncthreads();
    #pragma unroll
    for (int kk = 0; kk < 16; kk++) {
      float4 a03 = *(const float4*)&A_s[kk][ty * 8];
      float4 a47 = *(const float4*)&A_s[kk][ty * 8 + 4];
      float4 bv  = *(const float4*)&B_s[kk][tx * 4];
      float a[8] = {a03.x, a03.y, a03.z, a03.w, a47.x, a47.y, a47.z, a47.w};
      float bj[4] = {bv.x, bv.y, bv.z, bv.w};
      #pragma unroll
      for (int i = 0; i < 8; i++)
        #pragma unroll
        for (int j = 0; j < 4; j++)
          acc[i][j] += a[i] * bj[j];
    }
  }
  #pragma unroll
  for (int i = 0; i < 8; i++) {
    float4 o = {acc[i][0], acc[i][1], acc[i][2], acc[i][3]};
    *(float4*)(C + (size_t)(m0 + ty * 8 + i) * 256 + n0 + tx * 4) = o;
  }
}

// ---------------------------------------------------------------------------
// pack2: all fragment packing + combined bias in one launch. 370 blocks x 64.
// ---------------------------------------------------------------------------
__global__ __launch_bounds__(64) void pack2(
    const float* __restrict__ qkv_w, const float* __restrict__ Wf,
    const float* __restrict__ trans_w, const float* __restrict__ qkv_b,
    const float* __restrict__ Tt,
    unsigned short* __restrict__ allfrag,
    unsigned short* __restrict__ transfrag,
    float* __restrict__ bc)
{
  const int blk = blockIdx.x;
  const int lane = threadIdx.x;
  const float* B; int ldb, dstidx; unsigned short* dst; int kbase, n;
  if (blk < 192) {
    const int s = blk / 96, r = blk - s * 96;
    const int nt = r >> 2, ks = r & 3;
    B = qkv_w + (size_t)s * 128 * 384; ldb = 384;
    n = nt * 16 + (lane & 15);
    kbase = ks * 32 + ((lane >> 4) * 8);
    dst = allfrag + (size_t)s * FRAG_S;
    dstidx = nt * 4 + ks;
  } else if (blk < 272) {
    const int s = (blk - 192) / 40, r = (blk - 192) - s * 40;
    const int snt = r >> 2, ks = r & 3;
    B = Wf + (size_t)s * 32768; ldb = 256;
    n = snt * 16 + (lane & 15);
    kbase = ks * 32 + ((lane >> 4) * 8);
    dst = allfrag + (size_t)s * FRAG_S;
    dstidx = (24 + snt) * 4 + ks;
  } else if (blk < 368) {
    const int r = blk - 272;
    const int nt = r / 12, ks = r - nt * 12;
    B = trans_w; ldb = 128;
    n = nt * 16 + (lane & 15);
    kbase = ks * 32 + ((lane >> 4) * 8);
    dst = transfrag;
    dstidx = nt * 12 + ks;
  } else {
    const int s = blk - 368;
    for (int c = lane; c < 544; c += 64) {
      float v;
      if (c < 384) {
        v = qkv_b[s * 384 + c];
      } else {
        const float* bk = qkv_b + (size_t)s * 384 + 128;
        const float* T  = Tt + (size_t)s * 128 * 256 + (c - 384);
        float a = 0.f;
        #pragma unroll 4
        for (int e = 0; e < 128; e++) a += bk[e] * T[(size_t)e * 256];
        v = a;
      }
      bc[s * 544 + c] = v;
    }
    return;
  }
  unsigned v[4];
  #pragma unroll
  for (int h = 0; h < 4; h++) {
    const float x0 = B[(size_t)(kbase + 2 * h) * ldb + n];
    const float x1 = B[(size_t)(kbase + 2 * h + 1) * ldb + n];
    v[h] = f2bf(x0) | ((unsigned)f2bf(x1) << 16);
  }
  uint4 o = {v[0], v[1], v[2], v[3]};
  *(uint4*)(dst + ((size_t)dstidx * 64 + lane) * 8) = o;
}

// ---------------------------------------------------------------------------
// MEGA: one block (8 waves, 512 threads) per voxel; whole network per voxel.
// Weight frags read ONCE per block: phase-A wave = tile range {5,5,4,4,4,4,
// 4,4}, both row halves per frag; trans wave = ntile, both mtiles per frag.
// qk_s row (stride 440): q 0:128 (later f2) | k 128:256 | dk 256:406 |
// P (bf16 attn) 408:440.  V transposed in vT_s[f][j].
// ---------------------------------------------------------------------------
__global__ __launch_bounds__(512, 2) void mega(
    const float* __restrict__ inputs,
    const float* __restrict__ coords,
    const int*   __restrict__ groups,
    const unsigned short* __restrict__ allfrag,   // 2 x FRAG_S
    const float* __restrict__ bc,                 // 2 x 544
    const unsigned short* __restrict__ transfrag, // 8 nt x 12 ks
    const float* __restrict__ trans_b, const float* __restrict__ ln_g,
    const float* __restrict__ ln_b,
    float* __restrict__ out_all)
{
  __shared__ __align__(16) unsigned short feats_s[32][136];
  __shared__ __align__(16) unsigned short f1_s[32][136];
  __shared__ __align__(16) unsigned short qk_s[32][440];   // q|k|dk|P; f2->q
  __shared__ __align__(16) unsigned short vT_s[128][40];   // V^T [f][j]
  __shared__ __align__(16) float sc_s[32 * 33];
  __shared__ float cs[32][4];
  __shared__ float red_s[8][2][16][2];
  __shared__ float wmax_s[2][128];
  float* pooled_s = &red_s[0][0][0][0];  // alias: red dead before pooled

  const int t   = threadIdx.x;
  const int bid = blockIdx.x;
  const int b   = bid >> 9;
  const int g   = bid & 511;
  const int wv = t >> 6, lane = t & 63, quad = lane >> 4, col = lane & 15;

  // ---- stage feats (gather + fp32->bf16): 16 thr/row, 8 elems each ----
  {
    const int p = t >> 4, sg = t & 15;
    const int pid = groups[(b << 14) + g * KP + p];
    const float* src = inputs + ((size_t)(b << 14) + (size_t)pid) * D_ + sg * 8;
    float4 a0 = *(const float4*)(src);
    float4 a1 = *(const float4*)(src + 4);
    uint4 o0;
    o0.x = f2bf(a0.x) | ((unsigned)f2bf(a0.y) << 16);
    o0.y = f2bf(a0.z) | ((unsigned)f2bf(a0.w) << 16);
    o0.z = f2bf(a1.x) | ((unsigned)f2bf(a1.y) << 16);
    o0.w = f2bf(a1.z) | ((unsigned)f2bf(a1.w) << 16);
    *(uint4*)&feats_s[p][sg * 8] = o0;
  }
  if (t < 32) {
    const int pid = groups[(b << 14) + g * KP + t];
    const float* cp = coords + ((size_t)(b << 14) + (size_t)pid) * 3;
    cs[t][0] = cp[0]; cs[t][1] = cp[1]; cs[t][2] = cp[2];
  }
  __syncthreads();

  // ---- phase-A tile ranges: frag read once per block ----
  const int startsA[8] = {0, 5, 10, 14, 18, 22, 26, 30};
  const int cntsA[8]   = {5, 5, 4, 4, 4, 4, 4, 4};
  const int start = startsA[wv];
  const int cnt   = cntsA[wv];

  for (int layer = 0; layer < 2; layer++) {
    const uint4* fr = (const uint4*)(allfrag + (size_t)layer * FRAG_S) + lane;
    const float* bcl = bc + layer * 544;

    // A-frags for BOTH row halves (rows col and 16+col)
    uint4 avu[2][4];
    if (layer == 0) {
      #pragma unroll
      for (int ks = 0; ks < 4; ks++) {
        avu[0][ks] = *(const uint4*)&feats_s[col][ks * 32 + quad * 8];
        avu[1][ks] = *(const uint4*)&feats_s[16 + col][ks * 32 + quad * 8];
      }
    } else {
      #pragma unroll
      for (int ks = 0; ks < 4; ks++) {
        avu[0][ks] = *(const uint4*)&f1_s[col][ks * 32 + quad * 8];
        avu[1][ks] = *(const uint4*)&f1_s[16 + col][ks * 32 + quad * 8];
      }
    }

    #pragma unroll
    for (int u = 0; u < 5; u++) {
      if (u < cnt) {
        const int nt = start + u;
        f32x4 a0 = (f32x4){0.f, 0.f, 0.f, 0.f};
        f32x4 a1 = (f32x4){0.f, 0.f, 0.f, 0.f};
        #pragma unroll
        for (int ks = 0; ks < 4; ks++) {
          short8 bv = as_short8(fr[(nt * 4 + ks) * 64]);
          a0 = __builtin_amdgcn_mfma_f32_16x16x32_bf16(as_short8(avu[0][ks]), bv, a0, 0, 0, 0);
          a1 = __builtin_amdgcn_mfma_f32_16x16x32_bf16(as_short8(avu[1][ks]), bv, a1, 0, 0, 0);
        }
        const int cc = nt * 16 + col;
        const float bsv = bcl[cc];
        if (cc >= 256 && cc < 384) {          // V tile -> vT_s[f][j], b64 x2
          const unsigned lo0 = f2bf(a0[0] + bsv) | ((unsigned)f2bf(a0[1] + bsv) << 16);
          const unsigned hi0 = f2bf(a0[2] + bsv) | ((unsigned)f2bf(a0[3] + bsv) << 16);
          uint2 w0 = {lo0, hi0};
          *(uint2*)&vT_s[cc - 256][quad * 4] = w0;
          const unsigned lo1 = f2bf(a1[0] + bsv) | ((unsigned)f2bf(a1[1] + bsv) << 16);
          const unsigned hi1 = f2bf(a1[2] + bsv) | ((unsigned)f2bf(a1[3] + bsv) << 16);
          uint2 w1 = {lo1, hi1};
          *(uint2*)&vT_s[cc - 256][16 + quad * 4] = w1;
        } else {
          const int ccol = (cc < 256) ? cc : cc - 128;   // dk -> 256..405
          #pragma unroll
          for (int reg = 0; reg < 4; reg++) {
            qk_s[quad * 4 + reg][ccol]      = f2bf(a0[reg] + bsv);
            qk_s[16 + quad * 4 + reg][ccol] = f2bf(a1[reg] + bsv);
          }
        }
      }
    }
    __syncthreads();

    // scores via MFMA from LDS frags (waves 0..3)
    if (wv < 4) {
      const int ihalf = wv >> 1, jhalf = wv & 1;
      f32x4 sacc = {0.f, 0.f, 0.f, 0.f};
      #pragma unroll
      for (int ks = 0; ks < 4; ks++) {
        short8 qv = as_short8(*(const uint4*)&qk_s[ihalf * 16 + col][ks * 32 + quad * 8]);
        short8 kv = as_short8(*(const uint4*)&qk_s[jhalf * 16 + col][128 + ks * 32 + quad * 8]);
        sacc = __builtin_amdgcn_mfma_f32_16x16x32_bf16(qv, kv, sacc, 0, 0, 0);
      }
      const int j = jhalf * 16 + col;
      const float cjx = cs[j][0], cjy = cs[j][1], cjz = cs[j][2];
      #pragma unroll
      for (int reg = 0; reg < 4; reg++) {
        const int i = ihalf * 16 + quad * 4 + reg;
        const float dx = cs[i][0] - cjx;
        const float dy = cs[i][1] - cjy;
        const float dz = cs[i][2] - cjz;
        int ix = (int)floorf((dx + VSF) / QSF);
        int iy = (int)floorf((dy + VSF) / QSF);
        int iz = (int)floorf((dz + VSF) / QSF);
        ix = ix < 0 ? 0 : (ix > 49 ? 49 : ix);
        iy = iy < 0 ? 0 : (iy > 49 ? 49 : iy);
        iz = iz < 0 ? 0 : (iz > 49 ? 49 : iz);
        const unsigned short* dki = &qk_s[i][256];
        const float biasv = bu(dki[ix]) + bu(dki[50 + iy]) + bu(dki[100 + iz]);
        sc_s[i * 33 + j] = (sacc[reg] + biasv) * SCALE;
      }
    }
    __syncthreads();

    // softmax: 8 threads per row (t<256); emit bf16 P into qk_s cols 408..439
    if (t < 256) {
      const int p = t >> 3, sg = t & 7;
      float vals[4];
      float lm = -1e30f;
      #pragma unroll
      for (int u = 0; u < 4; u++) {
        vals[u] = sc_s[p * 33 + sg + u * 8];
        lm = fmaxf(lm, vals[u]);
      }
      lm = fmaxf(lm, __shfl_xor(lm, 1));
      lm = fmaxf(lm, __shfl_xor(lm, 2));
      lm = fmaxf(lm, __shfl_xor(lm, 4));
      float ls = 0.f;
      #pragma unroll
      for (int u = 0; u < 4; u++) { vals[u] = __expf(vals[u] - lm); ls += vals[u]; }
      ls += __shfl_xor(ls, 1);
      ls += __shfl_xor(ls, 2);
      ls += __shfl_xor(ls, 4);
      const float inv = 1.f / ls;
      #pragma unroll
      for (int u = 0; u < 4; u++)
        qk_s[p][408 + sg + u * 8] = f2bf(vals[u] * inv);
    }
    __syncthreads();

    // PV via MFMA: wave wv does mt=wv&1, ftiles (wv>>1)*2 + {0,1}
    {
      const int mt = wv & 1, ftb = (wv >> 1) * 2;
      unsigned short* dst_base = (layer == 0) ? &f1_s[0][0] : &qk_s[0][0];
      const int dst_ld = (layer == 0) ? 136 : 440;
      short8 pv = as_short8(*(const uint4*)&qk_s[mt * 16 + col][408 + quad * 8]);
      #pragma unroll
      for (int u = 0; u < 2; u++) {
        const int ft = ftb + u;
        short8 vv = as_short8(*(const uint4*)&vT_s[ft * 16 + col][quad * 8]);
        f32x4 o = (f32x4){0.f, 0.f, 0.f, 0.f};
        o = __builtin_amdgcn_mfma_f32_16x16x32_bf16(pv, vv, o, 0, 0, 0);
        const int f = ft * 16 + col;
        #pragma unroll
        for (int reg = 0; reg < 4; reg++) {
          const int i = mt * 16 + quad * 4 + reg;
          dst_base[i * dst_ld + f] = f2bf(o[reg]);
        }
      }
    }
    __syncthreads();
  }

  // ---- trans GEMM (K=384): wave = ntile, both mtiles per frag read ----
  const int nt = wv;
  f32x4 tacc[2];
  tacc[0] = (f32x4){0.f, 0.f, 0.f, 0.f};
  tacc[1] = (f32x4){0.f, 0.f, 0.f, 0.f};
  const uint4* tf = (const uint4*)transfrag + lane;
  #pragma unroll
  for (int ks = 0; ks < 12; ks++) {
    short8 bv = as_short8(tf[(nt * 12 + ks) * 64]);
    #pragma unroll
    for (int mt = 0; mt < 2; mt++) {
      const unsigned short* ar =
          (ks < 4) ? &feats_s[mt * 16 + col][(ks & 3) * 32 + quad * 8]
        : (ks < 8) ? &f1_s[mt * 16 + col][(ks & 3) * 32 + quad * 8]
                   : &qk_s[mt * 16 + col][(ks & 3) * 32 + quad * 8];  // f2
      short8 av = as_short8(*(const uint4*)ar);
      tacc[mt] = __builtin_amdgcn_mfma_f32_16x16x32_bf16(av, bv, tacc[mt], 0, 0, 0);
    }
  }
  // bias + LN partial stats (16 cols per wave, both mtiles)
  const int c = nt * 16 + col;
  const float bsv = trans_b[c], gg = ln_g[c], lb = ln_b[c];
  float s[2][4], ssq[2][4];
  #pragma unroll
  for (int mt = 0; mt < 2; mt++)
    #pragma unroll
    for (int reg = 0; reg < 4; reg++) {
      const float v = tacc[mt][reg] + bsv;
      tacc[mt][reg] = v;
      s[mt][reg] = v; ssq[mt][reg] = v * v;
    }
  #pragma unroll
  for (int mk = 1; mk <= 8; mk <<= 1) {
    #pragma unroll
    for (int mt = 0; mt < 2; mt++)
      #pragma unroll
      for (int reg = 0; reg < 4; reg++) {
        s[mt][reg]   += __shfl_xor(s[mt][reg],   mk);
        ssq[mt][reg] += __shfl_xor(ssq[mt][reg], mk);
      }
  }
  if (col == 0) {
    #pragma unroll
    for (int mt = 0; mt < 2; mt++)
      #pragma unroll
      for (int reg = 0; reg < 4; reg++) {
        red_s[wv][mt][quad * 4 + reg][0] = s[mt][reg];
        red_s[wv][mt][quad * 4 + reg][1] = ssq[mt][reg];
      }
  }
  __syncthreads();
  float mu[2][4], rstd[2][4];
  #pragma unroll
  for (int mt = 0; mt < 2; mt++)
    #pragma unroll
    for (int reg = 0; reg < 4; reg++) {
      float st = 0.f, sst = 0.f;
      #pragma unroll
      for (int w = 0; w < 8; w++) {
        st  += red_s[w][mt][quad * 4 + reg][0];
        sst += red_s[w][mt][quad * 4 + reg][1];
      }
      mu[mt][reg] = st * (1.f / 128.f);
      const float var = sst * (1.f / 128.f) - mu[mt][reg] * mu[mt][reg];
      rstd[mt][reg] = rsqrtf(var + 1e-5f);
    }
  // LN + ReLU + column max over 16 rows of each mtile
  float cm[2];
  #pragma unroll
  for (int mt = 0; mt < 2; mt++) {
    float mx = 0.f;   // ReLU floor
    #pragma unroll
    for (int reg = 0; reg < 4; reg++) {
      float v = (tacc[mt][reg] - mu[mt][reg]) * rstd[mt][reg] * gg + lb;
      v = fmaxf(v, 0.f);
      mx = fmaxf(mx, v);
    }
    cm[mt] = mx;
  }
  #pragma unroll
  for (int mt = 0; mt < 2; mt++) {
    cm[mt] = fmaxf(cm[mt], __shfl_xor(cm[mt], 16));
    cm[mt] = fmaxf(cm[mt], __shfl_xor(cm[mt], 32));
  }
  __syncthreads();   // all red_s reads done (pooled aliases red_s)
  if (quad == 0) {
    #pragma unroll
    for (int mt = 0; mt < 2; mt++)
      wmax_s[mt][c] = cm[mt];
  }
  __syncthreads();

  // pooled = max over both row halves; grid-reordered out write
  if (t < 128) {
    const int cc = t;
    const float mx = fmaxf(wmax_s[0][cc], wmax_s[1][cc]);
    pooled_s[cc] = mx;
    const int mm = g >> 6, nn = (g >> 3) & 7, tt2 = g & 7;
    const int opos = tt2 * 64 + nn * 8 + mm;
    out_all[((size_t)b * G_ + opos) * D_ + cc] = mx;
  }
  __syncthreads();

  // scatter pooled to every point (for_ret); 256 threads, 16 floats each
  if (t < 256) {
    const int p = t >> 3, sg = t & 7;
    const int pid = groups[(b << 14) + g * KP + p];
    float* dst = out_all + (size_t)BB * G_ * D_
               + ((size_t)(b << 14) + (size_t)pid) * D_ + sg * 16;
    #pragma unroll
    for (int u = 0; u < 4; u++)
      *(float4*)(dst + u * 4) = *(const float4*)&pooled_s[sg * 16 + u * 4];
  }
}

// ---------------------------------------------------------------------------
extern "C" void kernel_launch(void* const* d_in, const int* in_sizes, int n_in,
                              void* d_out, int out_size, void* d_ws, size_t ws_size,
                              hipStream_t stream) {
  const float* inputs  = (const float*)d_in[0];
  const float* coords  = (const float*)d_in[1];
  const float* qkv_w   = (const float*)d_in[2];   // [2,128,384]
  const float* qkv_b   = (const float*)d_in[3];   // [2,384]
  const float* tbl_x   = (const float*)d_in[4];   // [2,3,50,128]
  const float* tbl_y   = (const float*)d_in[5];
  const float* tbl_z   = (const float*)d_in[6];
  const float* trans_w = (const float*)d_in[7];   // [384,128]
  const float* trans_b = (const float*)d_in[8];
  const float* ln_g    = (const float*)d_in[9];
  const float* ln_b    = (const float*)d_in[10];
  const int*   groups  = (const int*)d_in[11];    // [2,512,32] flat

  float* out = (float*)d_out;
  unsigned short* allfrag   = (unsigned short*)d_ws;       // 2*FRAG_S
  unsigned short* transfrag = allfrag + 2 * FRAG_S;        // 96*512
  float* Tt  = (float*)(transfrag + 96 * 512);             // 2*128*256 f32
  float* Wf  = Tt + (size_t)2 * 128 * 256;                 // 2*128*256 f32
  float* bc  = Wf + (size_t)2 * 128 * 256;                 // 2*544 f32

  // ---- prep (weights only) ----
  prep_tt<<<256, 256, 0, stream>>>(tbl_x, tbl_y, tbl_z, Tt);
  wf_gemm<<<dim3(2, 2, 2), 256, 0, stream>>>(qkv_w, Tt, Wf);
  pack2<<<370, 64, 0, stream>>>(qkv_w, Wf, trans_w, qkv_b, Tt,
                                allfrag, transfrag, bc);

  // ---- whole network, one kernel ----
  mega<<<BB * G_, 512, 0, stream>>>(inputs, coords, groups, allfrag, bc,
                                    transfrag, trans_b, ln_g, ln_b, out);
}

// Round 13
// 165.325 us; speedup vs baseline: 1.4962x; 1.0167x over previous
//
#include <hip/hip_runtime.h>
#include <cstddef>

// Voxel encoder: B=2, N=16384, G=512 voxels x K=32 pts, d=128, S=2 layers.
// Round 13: r12 mega (47us) + software-pipelined weight-frag loads.
// VGPR=60 in r12 showed the compiler serialized L2 frag loads (load->wait
// ~250cyc->MFMA per tile; trans had 12 such chains). Phase A now prefetches
// tile u+1's B-frags before tile u's MFMAs; trans processes ks in groups of
// 4 with next-group prefetch. RULE (r8/r10): never force min-waves>2.

#define D_   128
#define VSF  0.25f
#define QSF  0.01f
#define LQ   50
#define G_   512
#define KP   32
#define BB   2
#define NP   16384
#define MT   32768
#define SCALE 0.08838834764831845f   // 1/sqrt(128)
#define NT_ALL 34           // 24 qkv tiles + 10 dk tiles (cols 0..543)
#define FRAG_S (NT_ALL * 4 * 64 * 8)   // ushorts per layer frag buffer

using short8 = __attribute__((ext_vector_type(8))) short;
using f32x4  = __attribute__((ext_vector_type(4))) float;

__device__ inline unsigned short f2bf(float x) {
  unsigned u = __builtin_bit_cast(unsigned, x);
  u += 0x7fffu + ((u >> 16) & 1u);      // round-to-nearest-even
  return (unsigned short)(u >> 16);
}
__device__ inline float bu(unsigned short h) {
  return __builtin_bit_cast(float, (unsigned)h << 16);
}
__device__ inline short8 as_short8(uint4 v) {
  union { uint4 u; short8 s; } x; x.u = v; return x.s;
}

// ---------------------------------------------------------------------------
// Transpose the (s,1) table slices into Tt[s][e=128][c=256], c = axis*50+l,
// zero-padded for c in [150,256). grid = 256 (s*128+e), block = 256 (c).
// ---------------------------------------------------------------------------
__global__ __launch_bounds__(256) void prep_tt(
    const float* __restrict__ tbl_x, const float* __restrict__ tbl_y,
    const float* __restrict__ tbl_z, float* __restrict__ Tt)
{
  const int c = threadIdx.x;
  const int s = blockIdx.x >> 7;
  const int e = blockIdx.x & 127;
  float v = 0.f;
  if (c < 150) {
    const int axis = c / 50, l = c - axis * 50;
    const float* tb = (axis == 0 ? tbl_x : (axis == 1 ? tbl_y : tbl_z));
    v = tb[(((size_t)s * 3 + 1) * LQ + l) * D_ + e];
  }
  Tt[((size_t)(s * 128 + e)) * 256 + c] = v;
}

// ---------------------------------------------------------------------------
// Wf = Wk @ Tt (fp32, both layers). grid=(2,2,2): x=m-tile, y=n-tile, z=s.
// ---------------------------------------------------------------------------
__global__ __launch_bounds__(256) void wf_gemm(
    const float* __restrict__ qkv_w, const float* __restrict__ Tt,
    float* __restrict__ Wf)
{
  __shared__ __align__(16) float A_s[16][68];
  __shared__ __align__(16) float B_s[16][132];
  const int t  = threadIdx.x;
  const int s  = blockIdx.z;
  const float* A = qkv_w + (size_t)s * 128 * 384 + 128;   // Wk rows, lda=384
  const float* B = Tt + (size_t)s * 128 * 256;
  float* C       = Wf + (size_t)s * 128 * 256;
  const int m0 = blockIdx.x * 64;
  const int n0 = blockIdx.y * 128;
  const int r  = t >> 2;
  const int kq = (t & 3) * 4;
  const float* arow = A + (size_t)(m0 + r) * 384;
  const int kkb = t >> 4;
  const int cb  = (t & 15) * 8;
  const float* wbase = B + (size_t)kkb * 256 + n0 + cb;
  const int tx = t & 31, ty = t >> 5;

  float acc[8][4];
  #pragma unroll
  for (int i = 0; i < 8; i++)
    #pragma unroll
    for (int j = 0; j < 4; j++) acc[i][j] = 0.f;

  for (int k0 = 0; k0 < 128; k0 += 16) {
    float4 av = *(const float4*)(arow + k0 + kq);
    float4 b0 = *(const float4*)(wbase + (size_t)k0 * 256);
    float4 b1 = *(const float4*)(wbase + (size_t)k0 * 256 + 4);
    __syncthreads();
    A_s[kq + 0][r] = av.x;
    A_s[kq + 1][r] = av.y;
    A_s[kq + 2][r] = av.z;
    A_s[kq + 3][r] = av.w;
    *(float4*)&B_s[kkb][cb]     = b0;
    *(float4*)&B_s[kkb][cb + 4] = b1;
    __syncthreads();
    #pragma unroll
    for (int kk = 0; kk < 16; kk++) {
      float4 a03 = *(const float4*)&A_s[kk][ty * 8];
      float4 a47 = *(const float4*)&A_s[kk][ty * 8 + 4];
      float4 bv  = *(const float4*)&B_s[kk][tx * 4];
      float a[8] = {a03.x, a03.y, a03.z, a03.w, a47.x, a47.y, a47.z, a47.w};
      float bj[4] = {bv.x, bv.y, bv.z, bv.w};
      #pragma unroll
      for (int i = 0; i < 8; i++)
        #pragma unroll
        for (int j = 0; j < 4; j++)
          acc[i][j] += a[i] * bj[j];
    }
  }
  #pragma unroll
  for (int i = 0; i < 8; i++) {
    float4 o = {acc[i][0], acc[i][1], acc[i][2], acc[i][3]};
    *(float4*)(C + (size_t)(m0 + ty * 8 + i) * 256 + n0 + tx * 4) = o;
  }
}

// ---------------------------------------------------------------------------
// pack2: all fragment packing + combined bias in one launch. 370 blocks x 64.
// ---------------------------------------------------------------------------
__global__ __launch_bounds__(64) void pack2(
    const float* __restrict__ qkv_w, const float* __restrict__ Wf,
    const float* __restrict__ trans_w, const float* __restrict__ qkv_b,
    const float* __restrict__ Tt,
    unsigned short* __restrict__ allfrag,
    unsigned short* __restrict__ transfrag,
    float* __restrict__ bc)
{
  const int blk = blockIdx.x;
  const int lane = threadIdx.x;
  const float* B; int ldb, dstidx; unsigned short* dst; int kbase, n;
  if (blk < 192) {
    const int s = blk / 96, r = blk - s * 96;
    const int nt = r >> 2, ks = r & 3;
    B = qkv_w + (size_t)s * 128 * 384; ldb = 384;
    n = nt * 16 + (lane & 15);
    kbase = ks * 32 + ((lane >> 4) * 8);
    dst = allfrag + (size_t)s * FRAG_S;
    dstidx = nt * 4 + ks;
  } else if (blk < 272) {
    const int s = (blk - 192) / 40, r = (blk - 192) - s * 40;
    const int snt = r >> 2, ks = r & 3;
    B = Wf + (size_t)s * 32768; ldb = 256;
    n = snt * 16 + (lane & 15);
    kbase = ks * 32 + ((lane >> 4) * 8);
    dst = allfrag + (size_t)s * FRAG_S;
    dstidx = (24 + snt) * 4 + ks;
  } else if (blk < 368) {
    const int r = blk - 272;
    const int nt = r / 12, ks = r - nt * 12;
    B = trans_w; ldb = 128;
    n = nt * 16 + (lane & 15);
    kbase = ks * 32 + ((lane >> 4) * 8);
    dst = transfrag;
    dstidx = nt * 12 + ks;
  } else {
    const int s = blk - 368;
    for (int c = lane; c < 544; c += 64) {
      float v;
      if (c < 384) {
        v = qkv_b[s * 384 + c];
      } else {
        const float* bk = qkv_b + (size_t)s * 384 + 128;
        const float* T  = Tt + (size_t)s * 128 * 256 + (c - 384);
        float a = 0.f;
        #pragma unroll 4
        for (int e = 0; e < 128; e++) a += bk[e] * T[(size_t)e * 256];
        v = a;
      }
      bc[s * 544 + c] = v;
    }
    return;
  }
  unsigned v[4];
  #pragma unroll
  for (int h = 0; h < 4; h++) {
    const float x0 = B[(size_t)(kbase + 2 * h) * ldb + n];
    const float x1 = B[(size_t)(kbase + 2 * h + 1) * ldb + n];
    v[h] = f2bf(x0) | ((unsigned)f2bf(x1) << 16);
  }
  uint4 o = {v[0], v[1], v[2], v[3]};
  *(uint4*)(dst + ((size_t)dstidx * 64 + lane) * 8) = o;
}

// ---------------------------------------------------------------------------
// MEGA: one block (8 waves, 512 threads) per voxel; whole network per voxel.
// Weight frags read once per block, loads software-pipelined (prefetch next
// tile/group before current MFMAs). qk_s row (stride 440): q 0:128 (later
// f2) | k 128:256 | dk 256:406 | P (bf16) 408:440. V transposed in vT_s.
// ---------------------------------------------------------------------------
__global__ __launch_bounds__(512, 2) void mega(
    const float* __restrict__ inputs,
    const float* __restrict__ coords,
    const int*   __restrict__ groups,
    const unsigned short* __restrict__ allfrag,   // 2 x FRAG_S
    const float* __restrict__ bc,                 // 2 x 544
    const unsigned short* __restrict__ transfrag, // 8 nt x 12 ks
    const float* __restrict__ trans_b, const float* __restrict__ ln_g,
    const float* __restrict__ ln_b,
    float* __restrict__ out_all)
{
  __shared__ __align__(16) unsigned short feats_s[32][136];
  __shared__ __align__(16) unsigned short f1_s[32][136];
  __shared__ __align__(16) unsigned short qk_s[32][440];   // q|k|dk|P; f2->q
  __shared__ __align__(16) unsigned short vT_s[128][40];   // V^T [f][j]
  __shared__ __align__(16) float sc_s[32 * 33];
  __shared__ float cs[32][4];
  __shared__ float red_s[8][2][16][2];
  __shared__ float wmax_s[2][128];
  float* pooled_s = &red_s[0][0][0][0];  // alias: red dead before pooled

  const int t   = threadIdx.x;
  const int bid = blockIdx.x;
  const int b   = bid >> 9;
  const int g   = bid & 511;
  const int wv = t >> 6, lane = t & 63, quad = lane >> 4, col = lane & 15;

  // ---- stage feats (gather + fp32->bf16): 16 thr/row, 8 elems each ----
  {
    const int p = t >> 4, sg = t & 15;
    const int pid = groups[(b << 14) + g * KP + p];
    const float* src = inputs + ((size_t)(b << 14) + (size_t)pid) * D_ + sg * 8;
    float4 a0 = *(const float4*)(src);
    float4 a1 = *(const float4*)(src + 4);
    uint4 o0;
    o0.x = f2bf(a0.x) | ((unsigned)f2bf(a0.y) << 16);
    o0.y = f2bf(a0.z) | ((unsigned)f2bf(a0.w) << 16);
    o0.z = f2bf(a1.x) | ((unsigned)f2bf(a1.y) << 16);
    o0.w = f2bf(a1.z) | ((unsigned)f2bf(a1.w) << 16);
    *(uint4*)&feats_s[p][sg * 8] = o0;
  }
  if (t < 32) {
    const int pid = groups[(b << 14) + g * KP + t];
    const float* cp = coords + ((size_t)(b << 14) + (size_t)pid) * 3;
    cs[t][0] = cp[0]; cs[t][1] = cp[1]; cs[t][2] = cp[2];
  }
  __syncthreads();

  // ---- phase-A tile ranges: frag read once per block ----
  const int startsA[8] = {0, 5, 10, 14, 18, 22, 26, 30};
  const int cntsA[8]   = {5, 5, 4, 4, 4, 4, 4, 4};
  const int start = startsA[wv];
  const int cnt   = cntsA[wv];

  for (int layer = 0; layer < 2; layer++) {
    const uint4* fr = (const uint4*)(allfrag + (size_t)layer * FRAG_S) + lane;
    const float* bcl = bc + layer * 544;

    // A-frags for BOTH row halves (rows col and 16+col)
    uint4 avu[2][4];
    if (layer == 0) {
      #pragma unroll
      for (int ks = 0; ks < 4; ks++) {
        avu[0][ks] = *(const uint4*)&feats_s[col][ks * 32 + quad * 8];
        avu[1][ks] = *(const uint4*)&feats_s[16 + col][ks * 32 + quad * 8];
      }
    } else {
      #pragma unroll
      for (int ks = 0; ks < 4; ks++) {
        avu[0][ks] = *(const uint4*)&f1_s[col][ks * 32 + quad * 8];
        avu[1][ks] = *(const uint4*)&f1_s[16 + col][ks * 32 + quad * 8];
      }
    }

    // Phase A with depth-1 prefetch of next tile's B-frags
    uint4 bvc[4];
    #pragma unroll
    for (int ks = 0; ks < 4; ks++) bvc[ks] = fr[(start * 4 + ks) * 64];

    for (int u = 0; u < cnt; u++) {
      const int ntn = start + ((u + 1 < cnt) ? (u + 1) : u);
      uint4 bvn[4];
      #pragma unroll
      for (int ks = 0; ks < 4; ks++) bvn[ks] = fr[(ntn * 4 + ks) * 64];

      f32x4 a0 = (f32x4){0.f, 0.f, 0.f, 0.f};
      f32x4 a1 = (f32x4){0.f, 0.f, 0.f, 0.f};
      #pragma unroll
      for (int ks = 0; ks < 4; ks++) {
        short8 bv = as_short8(bvc[ks]);
        a0 = __builtin_amdgcn_mfma_f32_16x16x32_bf16(as_short8(avu[0][ks]), bv, a0, 0, 0, 0);
        a1 = __builtin_amdgcn_mfma_f32_16x16x32_bf16(as_short8(avu[1][ks]), bv, a1, 0, 0, 0);
      }
      const int nt = start + u;
      const int cc = nt * 16 + col;
      const float bsv = bcl[cc];
      if (cc >= 256 && cc < 384) {          // V tile -> vT_s[f][j], b64 x2
        const unsigned lo0 = f2bf(a0[0] + bsv) | ((unsigned)f2bf(a0[1] + bsv) << 16);
        const unsigned hi0 = f2bf(a0[2] + bsv) | ((unsigned)f2bf(a0[3] + bsv) << 16);
        uint2 w0 = {lo0, hi0};
        *(uint2*)&vT_s[cc - 256][quad * 4] = w0;
        const unsigned lo1 = f2bf(a1[0] + bsv) | ((unsigned)f2bf(a1[1] + bsv) << 16);
        const unsigned hi1 = f2bf(a1[2] + bsv) | ((unsigned)f2bf(a1[3] + bsv) << 16);
        uint2 w1 = {lo1, hi1};
        *(uint2*)&vT_s[cc - 256][16 + quad * 4] = w1;
      } else {
        const int ccol = (cc < 256) ? cc : cc - 128;   // dk -> 256..405
        #pragma unroll
        for (int reg = 0; reg < 4; reg++) {
          qk_s[quad * 4 + reg][ccol]      = f2bf(a0[reg] + bsv);
          qk_s[16 + quad * 4 + reg][ccol] = f2bf(a1[reg] + bsv);
        }
      }
      #pragma unroll
      for (int ks = 0; ks < 4; ks++) bvc[ks] = bvn[ks];
    }
    __syncthreads();

    // scores via MFMA from LDS frags (waves 0..3)
    if (wv < 4) {
      const int ihalf = wv >> 1, jhalf = wv & 1;
      f32x4 sacc = {0.f, 0.f, 0.f, 0.f};
      #pragma unroll
      for (int ks = 0; ks < 4; ks++) {
        short8 qv = as_short8(*(const uint4*)&qk_s[ihalf * 16 + col][ks * 32 + quad * 8]);
        short8 kv = as_short8(*(const uint4*)&qk_s[jhalf * 16 + col][128 + ks * 32 + quad * 8]);
        sacc = __builtin_amdgcn_mfma_f32_16x16x32_bf16(qv, kv, sacc, 0, 0, 0);
      }
      const int j = jhalf * 16 + col;
      const float cjx = cs[j][0], cjy = cs[j][1], cjz = cs[j][2];
      #pragma unroll
      for (int reg = 0; reg < 4; reg++) {
        const int i = ihalf * 16 + quad * 4 + reg;
        const float dx = cs[i][0] - cjx;
        const float dy = cs[i][1] - cjy;
        const float dz = cs[i][2] - cjz;
        int ix = (int)floorf((dx + VSF) / QSF);
        int iy = (int)floorf((dy + VSF) / QSF);
        int iz = (int)floorf((dz + VSF) / QSF);
        ix = ix < 0 ? 0 : (ix > 49 ? 49 : ix);
        iy = iy < 0 ? 0 : (iy > 49 ? 49 : iy);
        iz = iz < 0 ? 0 : (iz > 49 ? 49 : iz);
        const unsigned short* dki = &qk_s[i][256];
        const float biasv = bu(dki[ix]) + bu(dki[50 + iy]) + bu(dki[100 + iz]);
        sc_s[i * 33 + j] = (sacc[reg] + biasv) * SCALE;
      }
    }
    __syncthreads();

    // softmax: 8 threads per row (t<256); emit bf16 P into qk_s cols 408..439
    if (t < 256) {
      const int p = t >> 3, sg = t & 7;
      float vals[4];
      float lm = -1e30f;
      #pragma unroll
      for (int u = 0; u < 4; u++) {
        vals[u] = sc_s[p * 33 + sg + u * 8];
        lm = fmaxf(lm, vals[u]);
      }
      lm = fmaxf(lm, __shfl_xor(lm, 1));
      lm = fmaxf(lm, __shfl_xor(lm, 2));
      lm = fmaxf(lm, __shfl_xor(lm, 4));
      float ls = 0.f;
      #pragma unroll
      for (int u = 0; u < 4; u++) { vals[u] = __expf(vals[u] - lm); ls += vals[u]; }
      ls += __shfl_xor(ls, 1);
      ls += __shfl_xor(ls, 2);
      ls += __shfl_xor(ls, 4);
      const float inv = 1.f / ls;
      #pragma unroll
      for (int u = 0; u < 4; u++)
        qk_s[p][408 + sg + u * 8] = f2bf(vals[u] * inv);
    }
    __syncthreads();

    // PV via MFMA: wave wv does mt=wv&1, ftiles (wv>>1)*2 + {0,1}
    {
      const int mt = wv & 1, ftb = (wv >> 1) * 2;
      unsigned short* dst_base = (layer == 0) ? &f1_s[0][0] : &qk_s[0][0];
      const int dst_ld = (layer == 0) ? 136 : 440;
      short8 pv = as_short8(*(const uint4*)&qk_s[mt * 16 + col][408 + quad * 8]);
      #pragma unroll
      for (int u = 0; u < 2; u++) {
        const int ft = ftb + u;
        short8 vv = as_short8(*(const uint4*)&vT_s[ft * 16 + col][quad * 8]);
        f32x4 o = (f32x4){0.f, 0.f, 0.f, 0.f};
        o = __builtin_amdgcn_mfma_f32_16x16x32_bf16(pv, vv, o, 0, 0, 0);
        const int f = ft * 16 + col;
        #pragma unroll
        for (int reg = 0; reg < 4; reg++) {
          const int i = mt * 16 + quad * 4 + reg;
          dst_base[i * dst_ld + f] = f2bf(o[reg]);
        }
      }
    }
    __syncthreads();
  }

  // ---- trans GEMM (K=384): wave = ntile, both mtiles per frag read;
  //      ks in groups of 4 with next-group prefetch ----
  const int nt = wv;
  f32x4 tacc[2];
  tacc[0] = (f32x4){0.f, 0.f, 0.f, 0.f};
  tacc[1] = (f32x4){0.f, 0.f, 0.f, 0.f};
  const uint4* tf = (const uint4*)transfrag + lane;
  uint4 grp[4];
  #pragma unroll
  for (int ks = 0; ks < 4; ks++) grp[ks] = tf[(nt * 12 + ks) * 64];
  #pragma unroll
  for (int ksb = 0; ksb < 12; ksb += 4) {
    uint4 nxt[4];
    if (ksb < 8) {
      #pragma unroll
      for (int ks = 0; ks < 4; ks++) nxt[ks] = tf[(nt * 12 + ksb + 4 + ks) * 64];
    }
    #pragma unroll
    for (int ks = 0; ks < 4; ks++) {
      const int kk = ksb + ks;
      short8 bv = as_short8(grp[ks]);
      #pragma unroll
      for (int mt = 0; mt < 2; mt++) {
        const unsigned short* ar =
            (kk < 4) ? &feats_s[mt * 16 + col][(kk & 3) * 32 + quad * 8]
          : (kk < 8) ? &f1_s[mt * 16 + col][(kk & 3) * 32 + quad * 8]
                     : &qk_s[mt * 16 + col][(kk & 3) * 32 + quad * 8];  // f2
        short8 av = as_short8(*(const uint4*)ar);
        tacc[mt] = __builtin_amdgcn_mfma_f32_16x16x32_bf16(av, bv, tacc[mt], 0, 0, 0);
      }
    }
    if (ksb < 8) {
      #pragma unroll
      for (int ks = 0; ks < 4; ks++) grp[ks] = nxt[ks];
    }
  }
  // bias + LN partial stats (16 cols per wave, both mtiles)
  const int c = nt * 16 + col;
  const float bsv = trans_b[c], gg = ln_g[c], lb = ln_b[c];
  float s[2][4], ssq[2][4];
  #pragma unroll
  for (int mt = 0; mt < 2; mt++)
    #pragma unroll
    for (int reg = 0; reg < 4; reg++) {
      const float v = tacc[mt][reg] + bsv;
      tacc[mt][reg] = v;
      s[mt][reg] = v; ssq[mt][reg] = v * v;
    }
  #pragma unroll
  for (int mk = 1; mk <= 8; mk <<= 1) {
    #pragma unroll
    for (int mt = 0; mt < 2; mt++)
      #pragma unroll
      for (int reg = 0; reg < 4; reg++) {
        s[mt][reg]   += __shfl_xor(s[mt][reg],   mk);
        ssq[mt][reg] += __shfl_xor(ssq[mt][reg], mk);
      }
  }
  if (col == 0) {
    #pragma unroll
    for (int mt = 0; mt < 2; mt++)
      #pragma unroll
      for (int reg = 0; reg < 4; reg++) {
        red_s[wv][mt][quad * 4 + reg][0] = s[mt][reg];
        red_s[wv][mt][quad * 4 + reg][1] = ssq[mt][reg];
      }
  }
  __syncthreads();
  float mu[2][4], rstd[2][4];
  #pragma unroll
  for (int mt = 0; mt < 2; mt++)
    #pragma unroll
    for (int reg = 0; reg < 4; reg++) {
      float st = 0.f, sst = 0.f;
      #pragma unroll
      for (int w = 0; w < 8; w++) {
        st  += red_s[w][mt][quad * 4 + reg][0];
        sst += red_s[w][mt][quad * 4 + reg][1];
      }
      mu[mt][reg] = st * (1.f / 128.f);
      const float var = sst * (1.f / 128.f) - mu[mt][reg] * mu[mt][reg];
      rstd[mt][reg] = rsqrtf(var + 1e-5f);
    }
  // LN + ReLU + column max over 16 rows of each mtile
  float cm[2];
  #pragma unroll
  for (int mt = 0; mt < 2; mt++) {
    float mx = 0.f;   // ReLU floor
    #pragma unroll
    for (int reg = 0; reg < 4; reg++) {
      float v = (tacc[mt][reg] - mu[mt][reg]) * rstd[mt][reg] * gg + lb;
      v = fmaxf(v, 0.f);
      mx = fmaxf(mx, v);
    }
    cm[mt] = mx;
  }
  #pragma unroll
  for (int mt = 0; mt < 2; mt++) {
    cm[mt] = fmaxf(cm[mt], __shfl_xor(cm[mt], 16));
    cm[mt] = fmaxf(cm[mt], __shfl_xor(cm[mt], 32));
  }
  __syncthreads();   // all red_s reads done (pooled aliases red_s)
  if (quad == 0) {
    #pragma unroll
    for (int mt = 0; mt < 2; mt++)
      wmax_s[mt][c] = cm[mt];
  }
  __syncthreads();

  // pooled = max over both row halves; grid-reordered out write
  if (t < 128) {
    const int cc = t;
    const float mx = fmaxf(wmax_s[0][cc], wmax_s[1][cc]);
    pooled_s[cc] = mx;
    const int mm = g >> 6, nn = (g >> 3) & 7, tt2 = g & 7;
    const int opos = tt2 * 64 + nn * 8 + mm;
    out_all[((size_t)b * G_ + opos) * D_ + cc] = mx;
  }
  __syncthreads();

  // scatter pooled to every point (for_ret); 256 threads, 16 floats each
  if (t < 256) {
    const int p = t >> 3, sg = t & 7;
    const int pid = groups[(b << 14) + g * KP + p];
    float* dst = out_all + (size_t)BB * G_ * D_
               + ((size_t)(b << 14) + (size_t)pid) * D_ + sg * 16;
    #pragma unroll
    for (int u = 0; u < 4; u++)
      *(float4*)(dst + u * 4) = *(const float4*)&pooled_s[sg * 16 + u * 4];
  }
}

// ---------------------------------------------------------------------------
extern "C" void kernel_launch(void* const* d_in, const int* in_sizes, int n_in,
                              void* d_out, int out_size, void* d_ws, size_t ws_size,
                              hipStream_t stream) {
  const float* inputs  = (const float*)d_in[0];
  const float* coords  = (const float*)d_in[1];
  const float* qkv_w   = (const float*)d_in[2];   // [2,128,384]
  const float* qkv_b   = (const float*)d_in[3];   // [2,384]
  const float* tbl_x   = (const float*)d_in[4];   // [2,3,50,128]
  const float* tbl_y   = (const float*)d_in[5];
  const float* tbl_z   = (const float*)d_in[6];
  const float* trans_w = (const float*)d_in[7];   // [384,128]
  const float* trans_b = (const float*)d_in[8];
  const float* ln_g    = (const float*)d_in[9];
  const float* ln_b    = (const float*)d_in[10];
  const int*   groups  = (const int*)d_in[11];    // [2,512,32] flat

  float* out = (float*)d_out;
  unsigned short* allfrag   = (unsigned short*)d_ws;       // 2*FRAG_S
  unsigned short* transfrag = allfrag + 2 * FRAG_S;        // 96*512
  float* Tt  = (float*)(transfrag + 96 * 512);             // 2*128*256 f32
  float* Wf  = Tt + (size_t)2 * 128 * 256;                 // 2*128*256 f32
  float* bc  = Wf + (size_t)2 * 128 * 256;                 // 2*544 f32

  // ---- prep (weights only) ----
  prep_tt<<<256, 256, 0, stream>>>(tbl_x, tbl_y, tbl_z, Tt);
  wf_gemm<<<dim3(2, 2, 2), 256, 0, stream>>>(qkv_w, Tt, Wf);
  pack2<<<370, 64, 0, stream>>>(qkv_w, Wf, trans_w, qkv_b, Tt,
                                allfrag, transfrag, bc);

  // ---- whole network, one kernel ----
  mega<<<BB * G_, 512, 0, stream>>>(inputs, coords, groups, allfrag, bc,
                                    transfrag, trans_b, ln_g, ln_b, out);
}